// Round 2
// baseline (619.087 us; speedup 1.0000x reference)
//
#include <hip/hip_runtime.h>
#include <hip/hip_bf16.h>

// Problem constants (fixed)
#define B_ 4
#define T_ 2048
#define D_ 1024
#define H_ 16
// DK = DV = 64

typedef __attribute__((ext_vector_type(8))) short bf16x8;
typedef __attribute__((ext_vector_type(4))) float f32x4;
typedef __attribute__((ext_vector_type(4))) unsigned short u16x4;

__device__ __forceinline__ unsigned short f2bf(float x) {
  union { float f; unsigned u; } v; v.f = x;
  unsigned r = v.u + 0x7fffu + ((v.u >> 16) & 1u);   // RNE
  return (unsigned short)(r >> 16);
}

__device__ __forceinline__ unsigned pack_bf2(float a, float b) {
  __hip_bfloat162 h = __float22bfloat162_rn(float2{a, b});
  union { __hip_bfloat162 h; unsigned u; } cv; cv.h = h; return cv.u;
}

__device__ __forceinline__ void gload_lds16(const void* g, void* l) {
  __builtin_amdgcn_global_load_lds(
      (const __attribute__((address_space(1))) unsigned int*)g,
      (__attribute__((address_space(3))) unsigned int*)l, 16, 0, 0);
}

#define MFMA16(a, b, c) __builtin_amdgcn_mfma_f32_16x16x32_bf16((a), (b), (c), 0, 0, 0)

// ---------------------------------------------------------------------------
// f32 -> bf16 flat convert (vectorized 4/lane)
// ---------------------------------------------------------------------------
__global__ __launch_bounds__(256) void conv_f32_bf16(
    const float4* __restrict__ src, u16x4* __restrict__ dst, int n4) {
  int i = blockIdx.x * 256 + threadIdx.x;
  int stride = gridDim.x * 256;
  for (; i < n4; i += stride) {
    float4 v = src[i];
    u16x4 o;
    o[0] = f2bf(v.x); o[1] = f2bf(v.y); o[2] = f2bf(v.z); o[3] = f2bf(v.w);
    dst[i] = o;
  }
}

// ---------------------------------------------------------------------------
// Weight transpose: src [H][D][DK] f32  ->  dst [H*DK][D] bf16  (B^T layout)
// ---------------------------------------------------------------------------
__global__ __launch_bounds__(256) void transpose_w(
    const float* __restrict__ src, unsigned short* __restrict__ dst,
    int D, int DK, int tilesD, int tilesK) {
  __shared__ float tile[64][65];
  int bid = blockIdx.x;
  int h = bid / (tilesD * tilesK);
  int rem = bid % (tilesD * tilesK);
  int dt = rem / tilesK, ktile = rem % tilesK;
  int d0 = dt * 64, k0 = ktile * 64;
  int tx = threadIdx.x & 63, ty = threadIdx.x >> 6;
  const float* s = src + (size_t)h * D * DK;
#pragma unroll
  for (int i = 0; i < 16; ++i) {
    int row = i * 4 + ty;
    tile[row][tx] = s[(size_t)(d0 + row) * DK + k0 + tx];
  }
  __syncthreads();
  unsigned short* dd = dst + (size_t)h * DK * D;
#pragma unroll
  for (int i = 0; i < 16; ++i) {
    int kk = i * 4 + ty;
    dd[(size_t)(k0 + kk) * D + d0 + tx] = f2bf(tile[tx][kk]);
  }
}

// ---------------------------------------------------------------------------
// GEMM: C[m][n] = sum_k A[m][k] * Bt[n][k],  K = 1024, bf16 in, tile 128x128
// mode 0: C f32 [M][1024]
// mode 1: C bf16 per-head [B,H,T,64]   (row = b*T+t, col = h*64+k)
// mode 2: C bf16 VhT [B,H,64,T]        (row = h*64+v, col = b*T+t)
// ---------------------------------------------------------------------------
__global__ __launch_bounds__(256) void gemm_bt(
    const unsigned short* __restrict__ A, const unsigned short* __restrict__ Bt,
    void* __restrict__ C, int nTilesN, int mode, float scale) {
  __shared__ unsigned short As[128 * 64];
  __shared__ unsigned short Bs[128 * 64];
  const int bid = blockIdx.x;
  const int bm = bid / nTilesN, bn = bid % nTilesN;
  const int m0 = bm * 128, n0 = bn * 128;
  const int tid = threadIdx.x;
  const int wave = tid >> 6, lane = tid & 63;
  const int wr = wave >> 1, wc = wave & 1;

  f32x4 acc[4][4];
#pragma unroll
  for (int m = 0; m < 4; ++m)
#pragma unroll
    for (int n = 0; n < 4; ++n) acc[m][n] = 0.f;

  const int soff = wave * 1024 + lane * 16;
  const char* Afr = (const char*)As + (wr * 64 + (lane & 15)) * 128 + (lane >> 4) * 16;
  const char* Bfr = (const char*)Bs + (wc * 64 + (lane & 15)) * 128 + (lane >> 4) * 16;

  for (int kt = 0; kt < 16; ++kt) {
    __syncthreads();
#pragma unroll
    for (int i = 0; i < 4; ++i) {
      int o2 = i * 4096 + soff;
      int row = o2 >> 7, colb = o2 & 127;
      gload_lds16((const char*)(A + (size_t)(m0 + row) * 1024 + kt * 64) + colb,
                  (char*)As + i * 4096 + wave * 1024);
      gload_lds16((const char*)(Bt + (size_t)(n0 + row) * 1024 + kt * 64) + colb,
                  (char*)Bs + i * 4096 + wave * 1024);
    }
    __syncthreads();
#pragma unroll
    for (int kk = 0; kk < 2; ++kk) {
      bf16x8 af[4], bf[4];
#pragma unroll
      for (int m = 0; m < 4; ++m) af[m] = *(const bf16x8*)(Afr + m * 2048 + kk * 64);
#pragma unroll
      for (int n = 0; n < 4; ++n) bf[n] = *(const bf16x8*)(Bfr + n * 2048 + kk * 64);
#pragma unroll
      for (int m = 0; m < 4; ++m)
#pragma unroll
        for (int n = 0; n < 4; ++n) acc[m][n] = MFMA16(af[m], bf[n], acc[m][n]);
    }
  }

  const int rbase = m0 + wr * 64 + ((lane >> 4) << 2);
  const int cbase = n0 + wc * 64 + (lane & 15);
#pragma unroll
  for (int m = 0; m < 4; ++m)
#pragma unroll
    for (int n = 0; n < 4; ++n)
#pragma unroll
      for (int r = 0; r < 4; ++r) {
        int row = rbase + m * 16 + r;
        int col = cbase + n * 16;
        float v = acc[m][n][r] * scale;
        if (mode == 0) {
          ((float*)C)[(size_t)row * 1024 + col] = v;
        } else if (mode == 1) {
          int b = row >> 11, t = row & 2047, h = col >> 6, k = col & 63;
          ((unsigned short*)C)[(((size_t)(b * H_ + h) * T_) + t) * 64 + k] = f2bf(v);
        } else {
          int h = row >> 6, vv = row & 63, b = col >> 11, t = col & 2047;
          ((unsigned short*)C)[(((size_t)(b * H_ + h) * 64) + vv) * T_ + t] = f2bf(v);
        }
      }
}

// ---------------------------------------------------------------------------
// Flash attention (causal), v2: NO K/V LDS staging, NO barriers.
// One block = (b, h, 64 q-rows), 4 waves x 16 q-rows, KV tile 64.
// K fragments read direct from global (contiguous 2KB per wave-load);
// V fragments read direct from VhT (64B chunks, L1/L2-served).
// Swapped QK^T: S^T = mfma(K, Q) -> softmax lane-local. Qh pre-scaled by
// log2(e)/8 -> pure exp2. Ps (P round-trip) is wave-private LDS, XOR-swizzled.
// Heavy-first qt order for causal load balance.
// ---------------------------------------------------------------------------
__global__ __launch_bounds__(256) void attn_fwd(
    const unsigned short* __restrict__ Qh, const unsigned short* __restrict__ Kh,
    const unsigned short* __restrict__ VhT, unsigned short* __restrict__ Abuf) {
  __shared__ unsigned short Ps[4][16 * 64]; // per-wave P [q][s], swizzled

  const int bid = blockIdx.x;
  const int qt = 31 - (bid & 31);          // heavy blocks dispatch first
  const int bh = bid >> 5;                 // b*H + h
  const int b = bh >> 4, h = bh & 15;
  const int tid = threadIdx.x;
  const int wave = tid >> 6, lane = tid & 63;
  const int lq = lane & 15;
  const int lk8 = (lane >> 4) * 8;
  const int q0 = qt * 64 + wave * 16;

  const unsigned short* Kbase = Kh + (size_t)bh * T_ * 64;
  const unsigned short* Vbase = VhT + (size_t)bh * 64 * T_;

  // Q fragment (B-operand of swapped QK^T): lane holds Q[q0+lq][k]
  bf16x8 qf0, qf1;
  {
    const unsigned short* qp = Qh + ((size_t)bh * T_ + q0 + lq) * 64 + lk8;
    qf0 = *(const bf16x8*)qp;
    qf1 = *(const bf16x8*)(qp + 32);
  }

  f32x4 o[4];
#pragma unroll
  for (int n = 0; n < 4; ++n) o[n] = 0.f;
  float m_run = -1e30f, l_run = 0.f;

  const int swz = (lq & 7) << 4;                       // byte XOR for Ps
  char* PsW = (char*)&Ps[wave][0] + lq * 128;          // row q = lq

  for (int kt = 0; kt <= qt; ++kt) {
    const int s0 = kt * 64;

    // ---- QK^T: S^T[s][q], K fragments direct from global ----
    f32x4 sacc[4];
#pragma unroll
    for (int c = 0; c < 4; ++c) {
      const unsigned short* kp = Kbase + (size_t)(s0 + c * 16 + lq) * 64 + lk8;
      bf16x8 ka0 = *(const bf16x8*)kp;
      bf16x8 ka1 = *(const bf16x8*)(kp + 32);
      f32x4 z = 0.f;
      z = MFMA16(ka0, qf0, z);
      sacc[c] = MFMA16(ka1, qf1, z);
    }

    if (kt == qt) {
      int qg = q0 + lq;
#pragma unroll
      for (int c = 0; c < 4; ++c)
#pragma unroll
        for (int r = 0; r < 4; ++r) {
          int sg = s0 + c * 16 + ((lane >> 4) << 2) + r;
          if (sg > qg) sacc[c][r] = -1e30f;
        }
    }

    // ---- online softmax (log2 domain), row q = lane&15 lane-local ----
    float pmax = sacc[0][0];
#pragma unroll
    for (int c = 0; c < 4; ++c)
#pragma unroll
      for (int r = 0; r < 4; ++r) pmax = fmaxf(pmax, sacc[c][r]);
    pmax = fmaxf(pmax, __shfl_xor(pmax, 16));
    pmax = fmaxf(pmax, __shfl_xor(pmax, 32));

    if (!__all(pmax - m_run <= 8.f)) {       // defer-max (T13): usually skip
      float mnew = fmaxf(m_run, pmax);
      float corr = __builtin_amdgcn_exp2f(m_run - mnew);
      float cr[4];
#pragma unroll
      for (int r = 0; r < 4; ++r) cr[r] = __shfl(corr, ((lane >> 4) << 2) + r);
#pragma unroll
      for (int n = 0; n < 4; ++n)
#pragma unroll
        for (int r = 0; r < 4; ++r) o[n][r] *= cr[r];
      l_run *= corr;
      m_run = mnew;
    }

    float psum = 0.f;
#pragma unroll
    for (int c = 0; c < 4; ++c)
#pragma unroll
      for (int r = 0; r < 4; ++r) {
        float p = __builtin_amdgcn_exp2f(sacc[c][r] - m_run);
        sacc[c][r] = p;
        psum += p;
      }
    psum += __shfl_xor(psum, 16);
    psum += __shfl_xor(psum, 32);
    l_run += psum;

    // ---- P -> wave-private LDS [q][s], swizzled (2-way max) ----
#pragma unroll
    for (int c = 0; c < 4; ++c) {
      uint2 pk;
      pk.x = pack_bf2(sacc[c][0], sacc[c][1]);
      pk.y = pack_bf2(sacc[c][2], sacc[c][3]);
      *(uint2*)(PsW + ((lk8 + c * 32) ^ swz)) = pk;   // lk8 bytes == (lane>>4)*8
    }

    // ---- O += P @ V, V fragments direct from global ----
#pragma unroll
    for (int ks = 0; ks < 2; ++ks) {
      bf16x8 pa = *(const bf16x8*)(PsW + ((ks * 64 + lk8 * 2) ^ swz));
#pragma unroll
      for (int n = 0; n < 4; ++n) {
        const unsigned short* vp = Vbase + (size_t)(n * 16 + lq) * T_ + s0 + ks * 32 + lk8;
        o[n] = MFMA16(pa, *(const bf16x8*)vp, o[n]);
      }
    }
  }

  // finalize: divide by l, write A [b*T+t][h*64+v] bf16
  float inv[4];
#pragma unroll
  for (int r = 0; r < 4; ++r)
    inv[r] = 1.0f / __shfl(l_run, ((lane >> 4) << 2) + r);
#pragma unroll
  for (int r = 0; r < 4; ++r) {
    int t = qt * 64 + wave * 16 + ((lane >> 4) << 2) + r;
    size_t base = ((size_t)b * T_ + t) * 1024 + h * 64 + lq;
#pragma unroll
    for (int n = 0; n < 4; ++n)
      Abuf[base + n * 16] = f2bf(o[n][r] * inv[r]);
  }
}

// ---------------------------------------------------------------------------
extern "C" void kernel_launch(void* const* d_in, const int* in_sizes, int n_in,
                              void* d_out, int out_size, void* d_ws, size_t ws_size,
                              hipStream_t stream) {
  (void)in_sizes; (void)n_in; (void)out_size; (void)ws_size;
  const float* Q  = (const float*)d_in[0];
  const float* K  = (const float*)d_in[1];
  const float* V  = (const float*)d_in[2];
  const float* WQ = (const float*)d_in[3];
  const float* WK = (const float*)d_in[4];
  const float* WV = (const float*)d_in[5];
  const float* WO = (const float*)d_in[6];
  float* out = (float*)d_out;
  char* ws = (char*)d_ws;

  const size_t SZ_ACT = (size_t)8192 * 1024 * 2;  // 16.78 MB
  const size_t SZ_W   = (size_t)1024 * 1024 * 2;  //  2.10 MB
  unsigned short* Qbf = (unsigned short*)(ws);
  unsigned short* Kbf = (unsigned short*)(ws + SZ_ACT);
  unsigned short* Vbf = (unsigned short*)(ws + 2 * SZ_ACT);
  unsigned short* WqT = (unsigned short*)(ws + 3 * SZ_ACT);
  unsigned short* WkT = (unsigned short*)(ws + 3 * SZ_ACT + SZ_W);
  unsigned short* WvT = (unsigned short*)(ws + 3 * SZ_ACT + 2 * SZ_W);
  unsigned short* WOt = (unsigned short*)(ws + 3 * SZ_ACT + 3 * SZ_W);
  unsigned short* Qh  = (unsigned short*)(ws + 3 * SZ_ACT + 4 * SZ_W);
  unsigned short* Kh  = (unsigned short*)(ws + 4 * SZ_ACT + 4 * SZ_W);
  unsigned short* VhT = (unsigned short*)(ws + 5 * SZ_ACT + 4 * SZ_W);
  unsigned short* Abuf = Qbf;  // Qbf dead after Q projection

  // 1) convert activations to bf16
  conv_f32_bf16<<<2048, 256, 0, stream>>>((const float4*)Q, (u16x4*)Qbf, 2097152);
  conv_f32_bf16<<<2048, 256, 0, stream>>>((const float4*)K, (u16x4*)Kbf, 2097152);
  conv_f32_bf16<<<2048, 256, 0, stream>>>((const float4*)V, (u16x4*)Vbf, 2097152);

  // 2) transpose weights to B^T bf16
  transpose_w<<<256, 256, 0, stream>>>(WQ, WqT, 1024, 64, 16, 1);
  transpose_w<<<256, 256, 0, stream>>>(WK, WkT, 1024, 64, 16, 1);
  transpose_w<<<256, 256, 0, stream>>>(WV, WvT, 1024, 64, 16, 1);
  transpose_w<<<256, 256, 0, stream>>>(WO, WOt, 1024, 1024, 16, 16);

  // 3) projections (Q scaled by log2(e)/sqrt(dk))
  const float qscale = 1.4426950408889634f / 8.0f;
  gemm_bt<<<512, 256, 0, stream>>>(Qbf, WqT, Qh, 8, 1, qscale);   // M=8192,N=1024
  gemm_bt<<<512, 256, 0, stream>>>(Kbf, WkT, Kh, 8, 1, 1.0f);
  gemm_bt<<<512, 256, 0, stream>>>(WvT, Vbf, VhT, 64, 2, 1.0f);   // M=1024,N=8192 -> VhT

  // 4) causal flash attention (no barriers, direct-global K/V)
  attn_fwd<<<2048, 256, 0, stream>>>(Qh, Kh, VhT, Abuf);

  // 5) output projection -> f32
  gemm_bt<<<512, 256, 0, stream>>>(Abuf, WOt, out, 8, 0, 1.0f);
}

// Round 3
// 335.652 us; speedup vs baseline: 1.8444x; 1.8444x over previous
//
#include <hip/hip_runtime.h>
#include <hip/hip_bf16.h>

// Problem constants (fixed)
#define B_ 4
#define T_ 2048
#define D_ 1024
#define H_ 16
// DK = DV = 64

typedef __attribute__((ext_vector_type(8))) short bf16x8;
typedef __attribute__((ext_vector_type(4))) float f32x4;
typedef __attribute__((ext_vector_type(4))) unsigned short u16x4;

__device__ __forceinline__ unsigned short f2bf(float x) {
  union { float f; unsigned u; } v; v.f = x;
  unsigned r = v.u + 0x7fffu + ((v.u >> 16) & 1u);   // RNE
  return (unsigned short)(r >> 16);
}

__device__ __forceinline__ unsigned pack_bf2(float a, float b) {
  __hip_bfloat162 h = __float22bfloat162_rn(float2{a, b});
  union { __hip_bfloat162 h; unsigned u; } cv; cv.h = h; return cv.u;
}

__device__ __forceinline__ void gload_lds16(const void* g, void* l) {
  __builtin_amdgcn_global_load_lds(
      (const __attribute__((address_space(1))) unsigned int*)g,
      (__attribute__((address_space(3))) unsigned int*)l, 16, 0, 0);
}

#define MFMA16(a, b, c) __builtin_amdgcn_mfma_f32_16x16x32_bf16((a), (b), (c), 0, 0, 0)

// ---------------------------------------------------------------------------
// f32 -> bf16 flat convert (vectorized 4/lane)
// ---------------------------------------------------------------------------
__global__ __launch_bounds__(256) void conv_f32_bf16(
    const float4* __restrict__ src, u16x4* __restrict__ dst, int n4) {
  int i = blockIdx.x * 256 + threadIdx.x;
  int stride = gridDim.x * 256;
  for (; i < n4; i += stride) {
    float4 v = src[i];
    u16x4 o;
    o[0] = f2bf(v.x); o[1] = f2bf(v.y); o[2] = f2bf(v.z); o[3] = f2bf(v.w);
    dst[i] = o;
  }
}

// ---------------------------------------------------------------------------
// Weight transpose: src [H][D][DK] f32  ->  dst [H*DK][D] bf16  (B^T layout)
// ---------------------------------------------------------------------------
__global__ __launch_bounds__(256) void transpose_w(
    const float* __restrict__ src, unsigned short* __restrict__ dst,
    int D, int DK, int tilesD, int tilesK) {
  __shared__ float tile[64][65];
  int bid = blockIdx.x;
  int h = bid / (tilesD * tilesK);
  int rem = bid % (tilesD * tilesK);
  int dt = rem / tilesK, ktile = rem % tilesK;
  int d0 = dt * 64, k0 = ktile * 64;
  int tx = threadIdx.x & 63, ty = threadIdx.x >> 6;
  const float* s = src + (size_t)h * D * DK;
#pragma unroll
  for (int i = 0; i < 16; ++i) {
    int row = i * 4 + ty;
    tile[row][tx] = s[(size_t)(d0 + row) * DK + k0 + tx];
  }
  __syncthreads();
  unsigned short* dd = dst + (size_t)h * DK * D;
#pragma unroll
  for (int i = 0; i < 16; ++i) {
    int kk = i * 4 + ty;
    dd[(size_t)(k0 + kk) * D + d0 + tx] = f2bf(tile[tx][kk]);
  }
}

// ---------------------------------------------------------------------------
// GEMM: C[m][n] = sum_k A[m][k] * Bt[n][k],  K = 1024, bf16 in, tile 128x128
// mode 0: C f32 [M][1024]
// mode 1: C bf16 per-head [B,H,T,64]   (row = b*T+t, col = h*64+k)
// mode 2: C bf16 VhT [B,H,64,T]        (row = h*64+v, col = b*T+t)
// ---------------------------------------------------------------------------
__global__ __launch_bounds__(256) void gemm_bt(
    const unsigned short* __restrict__ A, const unsigned short* __restrict__ Bt,
    void* __restrict__ C, int nTilesN, int mode, float scale) {
  __shared__ unsigned short As[128 * 64];
  __shared__ unsigned short Bs[128 * 64];
  const int bid = blockIdx.x;
  const int bm = bid / nTilesN, bn = bid % nTilesN;
  const int m0 = bm * 128, n0 = bn * 128;
  const int tid = threadIdx.x;
  const int wave = tid >> 6, lane = tid & 63;
  const int wr = wave >> 1, wc = wave & 1;

  f32x4 acc[4][4];
#pragma unroll
  for (int m = 0; m < 4; ++m)
#pragma unroll
    for (int n = 0; n < 4; ++n) acc[m][n] = 0.f;

  const int soff = wave * 1024 + lane * 16;
  const char* Afr = (const char*)As + (wr * 64 + (lane & 15)) * 128 + (lane >> 4) * 16;
  const char* Bfr = (const char*)Bs + (wc * 64 + (lane & 15)) * 128 + (lane >> 4) * 16;

  for (int kt = 0; kt < 16; ++kt) {
    __syncthreads();
#pragma unroll
    for (int i = 0; i < 4; ++i) {
      int o2 = i * 4096 + soff;
      int row = o2 >> 7, colb = o2 & 127;
      gload_lds16((const char*)(A + (size_t)(m0 + row) * 1024 + kt * 64) + colb,
                  (char*)As + i * 4096 + wave * 1024);
      gload_lds16((const char*)(Bt + (size_t)(n0 + row) * 1024 + kt * 64) + colb,
                  (char*)Bs + i * 4096 + wave * 1024);
    }
    __syncthreads();
#pragma unroll
    for (int kk = 0; kk < 2; ++kk) {
      bf16x8 af[4], bf[4];
#pragma unroll
      for (int m = 0; m < 4; ++m) af[m] = *(const bf16x8*)(Afr + m * 2048 + kk * 64);
#pragma unroll
      for (int n = 0; n < 4; ++n) bf[n] = *(const bf16x8*)(Bfr + n * 2048 + kk * 64);
#pragma unroll
      for (int m = 0; m < 4; ++m)
#pragma unroll
        for (int n = 0; n < 4; ++n) acc[m][n] = MFMA16(af[m], bf[n], acc[m][n]);
    }
  }

  const int rbase = m0 + wr * 64 + ((lane >> 4) << 2);
  const int cbase = n0 + wc * 64 + (lane & 15);
#pragma unroll
  for (int m = 0; m < 4; ++m)
#pragma unroll
    for (int n = 0; n < 4; ++n)
#pragma unroll
      for (int r = 0; r < 4; ++r) {
        int row = rbase + m * 16 + r;
        int col = cbase + n * 16;
        float v = acc[m][n][r] * scale;
        if (mode == 0) {
          ((float*)C)[(size_t)row * 1024 + col] = v;
        } else if (mode == 1) {
          int b = row >> 11, t = row & 2047, h = col >> 6, k = col & 63;
          ((unsigned short*)C)[(((size_t)(b * H_ + h) * T_) + t) * 64 + k] = f2bf(v);
        } else {
          int h = row >> 6, vv = row & 63, b = col >> 11, t = col & 2047;
          ((unsigned short*)C)[(((size_t)(b * H_ + h) * 64) + vv) * T_ + t] = f2bf(v);
        }
      }
}

// ---------------------------------------------------------------------------
// Flash attention (causal), v3: LDS-staged K/V, double-buffered, prefetched.
// One block = (b, h, 128 q-rows), 4 waves x 32 q (two 16-row frags each).
// K/V tiles 64x64 bf16, XOR-swizzled ((row&7)<<4) via pre-swizzled global
// source (linear LDS dest for global_load_lds, rule #21). One raw s_barrier +
// asm vmcnt(0) per KV tile (T3-lite 2-phase). K and V fragments read once,
// shared by both q-frags. Swapped QK^T -> lane-local softmax; defer-max T13.
// ---------------------------------------------------------------------------
__global__ __launch_bounds__(256) void attn_fwd(
    const unsigned short* __restrict__ Qh, const unsigned short* __restrict__ Kh,
    const unsigned short* __restrict__ VhT, unsigned short* __restrict__ Abuf) {
  __shared__ unsigned short Ks[2][64 * 64];   // [s][k], swizzled, 8KB each
  __shared__ unsigned short Vs[2][64 * 64];   // [v][s], swizzled, 8KB each
  __shared__ unsigned short Ps[4][32 * 64];   // per-wave P [q][s], swizzled

  const int bid = blockIdx.x;
  const int qb = 15 - (bid & 15);            // heavy blocks first
  const int bh = bid >> 4;                   // b*H + h
  const int b = bh >> 4, h = bh & 15;
  const int tid = threadIdx.x;
  const int wave = tid >> 6, lane = tid & 63;
  const int lq = lane & 15;
  const int hi = lane >> 4;
  const int q0w = qb * 128 + wave * 32;
  const int nkt = 2 * qb + 2;

  const char* Kbase = (const char*)(Kh + (size_t)bh * T_ * 64);
  const char* Vbase = (const char*)(VhT + (size_t)bh * 64 * T_);

  // staging geometry: LDS offset o covers the 8KB tile linearly; global src
  // column is inverse-swizzled so swizzled reads see the right data.
  int srow[2], scol[2], sdst[2];
#pragma unroll
  for (int i = 0; i < 2; ++i) {
    int o = i * 4096 + wave * 1024 + lane * 16;
    srow[i] = o >> 7;
    scol[i] = (o & 127) ^ ((srow[i] & 7) << 4);
    sdst[i] = i * 4096 + wave * 1024;        // wave-uniform dest (HW adds lane*16)
  }

  // Q fragments: frag j covers q rows [q0w + j*16, +16)
  bf16x8 qf[2][2];
#pragma unroll
  for (int j = 0; j < 2; ++j) {
    const unsigned short* qp = Qh + ((size_t)bh * T_ + q0w + j * 16 + lq) * 64 + hi * 8;
    qf[j][0] = *(const bf16x8*)qp;
    qf[j][1] = *(const bf16x8*)(qp + 32);
  }

  f32x4 o[2][4];
#pragma unroll
  for (int j = 0; j < 2; ++j)
#pragma unroll
    for (int n = 0; n < 4; ++n) o[j][n] = 0.f;
  float m_run[2] = {-1e30f, -1e30f}, l_run[2] = {0.f, 0.f};

  const int pswz = (lq & 7) << 4;

  auto stage = [&](int buf, int kt) {
#pragma unroll
    for (int i = 0; i < 2; ++i) {
      gload_lds16(Kbase + (size_t)(kt * 64 + srow[i]) * 128 + scol[i],
                  (char*)Ks[buf] + sdst[i]);
      gload_lds16(Vbase + (size_t)srow[i] * (T_ * 2) + kt * 128 + scol[i],
                  (char*)Vs[buf] + sdst[i]);
    }
  };

  // prologue: stage tile 0
  stage(0, 0);
  asm volatile("s_waitcnt vmcnt(0)" ::: "memory");
  __builtin_amdgcn_s_barrier();

  int cur = 0;
  for (int kt = 0; kt < nkt; ++kt) {
    const int s0 = kt * 64;
    if (kt + 1 < nkt) stage(cur ^ 1, kt + 1);   // prefetch overlaps compute

    const char* KsB = (const char*)Ks[cur];
    const char* VsB = (const char*)Vs[cur];
    const bool act0 = (s0 <= q0w + 15);
    const bool act1 = (s0 <= q0w + 31);

    // ---- QK^T both frags, K fragments read once ----
    f32x4 sc[2][4];
#pragma unroll
    for (int c = 0; c < 4; ++c) {
      int r = c * 16 + lq;
      const char* kb = KsB + r * 128;
      int sw = (r & 7) << 4;
      bf16x8 ka0 = *(const bf16x8*)(kb + ((hi * 16) ^ sw));
      bf16x8 ka1 = *(const bf16x8*)(kb + ((64 + hi * 16) ^ sw));
      if (act0) { f32x4 z = 0.f; z = MFMA16(ka0, qf[0][0], z); sc[0][c] = MFMA16(ka1, qf[0][1], z); }
      if (act1) { f32x4 z = 0.f; z = MFMA16(ka0, qf[1][0], z); sc[1][c] = MFMA16(ka1, qf[1][1], z); }
    }

    // ---- per-frag: mask, online softmax, P -> LDS ----
#pragma unroll
    for (int j = 0; j < 2; ++j) {
      const int q0j = q0w + j * 16;
      const bool act = (s0 <= q0j + 15);
      if (!act) continue;                      // wave-uniform

      if (s0 + 63 > q0j) {                     // diagonal tile: element mask
        int qg = q0j + lq;
#pragma unroll
        for (int c = 0; c < 4; ++c)
#pragma unroll
          for (int r = 0; r < 4; ++r) {
            int sg = s0 + c * 16 + hi * 4 + r;
            if (sg > qg) sc[j][c][r] = -1e30f;
          }
      }

      float pmax = sc[j][0][0];
#pragma unroll
      for (int c = 0; c < 4; ++c)
#pragma unroll
        for (int r = 0; r < 4; ++r) pmax = fmaxf(pmax, sc[j][c][r]);
      pmax = fmaxf(pmax, __shfl_xor(pmax, 16));
      pmax = fmaxf(pmax, __shfl_xor(pmax, 32));

      if (!__all(pmax - m_run[j] <= 8.f)) {    // defer-max (T13)
        float mnew = fmaxf(m_run[j], pmax);
        float corr = __builtin_amdgcn_exp2f(m_run[j] - mnew);
        float cr[4];
#pragma unroll
        for (int r = 0; r < 4; ++r) cr[r] = __shfl(corr, hi * 4 + r);
#pragma unroll
        for (int n = 0; n < 4; ++n)
#pragma unroll
          for (int r = 0; r < 4; ++r) o[j][n][r] *= cr[r];
        l_run[j] *= corr;
        m_run[j] = mnew;
      }

      float psum = 0.f;
#pragma unroll
      for (int c = 0; c < 4; ++c)
#pragma unroll
        for (int r = 0; r < 4; ++r) {
          float p = __builtin_amdgcn_exp2f(sc[j][c][r] - m_run[j]);
          sc[j][c][r] = p;
          psum += p;
        }
      psum += __shfl_xor(psum, 16);
      psum += __shfl_xor(psum, 32);
      l_run[j] += psum;

      char* pw = (char*)&Ps[wave][0] + (j * 16 + lq) * 128;
#pragma unroll
      for (int c = 0; c < 4; ++c) {
        uint2 pk;
        pk.x = pack_bf2(sc[j][c][0], sc[j][c][1]);
        pk.y = pack_bf2(sc[j][c][2], sc[j][c][3]);
        *(uint2*)(pw + ((c * 32 + hi * 8) ^ pswz)) = pk;
      }
    }

    // ---- PV: V fragments read once, shared by both frags ----
    const char* PsW = (const char*)&Ps[wave][0];
#pragma unroll
    for (int ks = 0; ks < 2; ++ks) {
      int pb = (ks * 64 + hi * 16) ^ pswz;
      bf16x8 pa0, pa1;
      if (act0) pa0 = *(const bf16x8*)(PsW + lq * 128 + pb);
      if (act1) pa1 = *(const bf16x8*)(PsW + (16 + lq) * 128 + pb);
#pragma unroll
      for (int n = 0; n < 4; ++n) {
        int rv = n * 16 + lq;
        bf16x8 vb = *(const bf16x8*)(VsB + rv * 128 + ((ks * 64 + hi * 16) ^ ((rv & 7) << 4)));
        if (act0) o[0][n] = MFMA16(pa0, vb, o[0][n]);
        if (act1) o[1][n] = MFMA16(pa1, vb, o[1][n]);
      }
    }

    // tile boundary: drain prefetch, sync all waves (raw barrier, no full drain
    // beyond the 4 outstanding prefetch loads)
    asm volatile("s_waitcnt vmcnt(0)" ::: "memory");
    __builtin_amdgcn_s_barrier();
    cur ^= 1;
  }

  // finalize: divide by l, write A [b*T+t][h*64+v] bf16
#pragma unroll
  for (int j = 0; j < 2; ++j) {
    float inv[4];
#pragma unroll
    for (int r = 0; r < 4; ++r)
      inv[r] = 1.0f / __shfl(l_run[j], hi * 4 + r);
#pragma unroll
    for (int r = 0; r < 4; ++r) {
      int t = qb * 128 + wave * 32 + j * 16 + hi * 4 + r;
      size_t base = ((size_t)b * T_ + t) * 1024 + h * 64 + lq;
#pragma unroll
      for (int n = 0; n < 4; ++n)
        Abuf[base + n * 16] = f2bf(o[j][n][r] * inv[r]);
    }
  }
}

// ---------------------------------------------------------------------------
extern "C" void kernel_launch(void* const* d_in, const int* in_sizes, int n_in,
                              void* d_out, int out_size, void* d_ws, size_t ws_size,
                              hipStream_t stream) {
  (void)in_sizes; (void)n_in; (void)out_size; (void)ws_size;
  const float* Q  = (const float*)d_in[0];
  const float* K  = (const float*)d_in[1];
  const float* V  = (const float*)d_in[2];
  const float* WQ = (const float*)d_in[3];
  const float* WK = (const float*)d_in[4];
  const float* WV = (const float*)d_in[5];
  const float* WO = (const float*)d_in[6];
  float* out = (float*)d_out;
  char* ws = (char*)d_ws;

  const size_t SZ_ACT = (size_t)8192 * 1024 * 2;  // 16.78 MB
  const size_t SZ_W   = (size_t)1024 * 1024 * 2;  //  2.10 MB
  unsigned short* Qbf = (unsigned short*)(ws);
  unsigned short* Kbf = (unsigned short*)(ws + SZ_ACT);
  unsigned short* Vbf = (unsigned short*)(ws + 2 * SZ_ACT);
  unsigned short* WqT = (unsigned short*)(ws + 3 * SZ_ACT);
  unsigned short* WkT = (unsigned short*)(ws + 3 * SZ_ACT + SZ_W);
  unsigned short* WvT = (unsigned short*)(ws + 3 * SZ_ACT + 2 * SZ_W);
  unsigned short* WOt = (unsigned short*)(ws + 3 * SZ_ACT + 3 * SZ_W);
  unsigned short* Qh  = (unsigned short*)(ws + 3 * SZ_ACT + 4 * SZ_W);
  unsigned short* Kh  = (unsigned short*)(ws + 4 * SZ_ACT + 4 * SZ_W);
  unsigned short* VhT = (unsigned short*)(ws + 5 * SZ_ACT + 4 * SZ_W);
  unsigned short* Abuf = Qbf;  // Qbf dead after Q projection

  // 1) convert activations to bf16
  conv_f32_bf16<<<2048, 256, 0, stream>>>((const float4*)Q, (u16x4*)Qbf, 2097152);
  conv_f32_bf16<<<2048, 256, 0, stream>>>((const float4*)K, (u16x4*)Kbf, 2097152);
  conv_f32_bf16<<<2048, 256, 0, stream>>>((const float4*)V, (u16x4*)Vbf, 2097152);

  // 2) transpose weights to B^T bf16
  transpose_w<<<256, 256, 0, stream>>>(WQ, WqT, 1024, 64, 16, 1);
  transpose_w<<<256, 256, 0, stream>>>(WK, WkT, 1024, 64, 16, 1);
  transpose_w<<<256, 256, 0, stream>>>(WV, WvT, 1024, 64, 16, 1);
  transpose_w<<<256, 256, 0, stream>>>(WO, WOt, 1024, 1024, 16, 16);

  // 3) projections (Q scaled by log2(e)/sqrt(dk))
  const float qscale = 1.4426950408889634f / 8.0f;
  gemm_bt<<<512, 256, 0, stream>>>(Qbf, WqT, Qh, 8, 1, qscale);   // M=8192,N=1024
  gemm_bt<<<512, 256, 0, stream>>>(Kbf, WkT, Kh, 8, 1, 1.0f);
  gemm_bt<<<512, 256, 0, stream>>>(WvT, Vbf, VhT, 64, 2, 1.0f);   // M=1024,N=8192 -> VhT

  // 4) causal flash attention (staged + swizzled + prefetched)
  attn_fwd<<<1024, 256, 0, stream>>>(Qh, Kh, VhT, Abuf);

  // 5) output projection -> f32
  gemm_bt<<<512, 256, 0, stream>>>(Abuf, WOt, out, 8, 0, 1.0f);
}

// Round 4
// 264.014 us; speedup vs baseline: 2.3449x; 1.2713x over previous
//
#include <hip/hip_runtime.h>
#include <hip/hip_bf16.h>

// Problem constants (fixed)
#define B_ 4
#define T_ 2048
#define D_ 1024
#define H_ 16
// DK = DV = 64

typedef __attribute__((ext_vector_type(8))) short bf16x8;
typedef __attribute__((ext_vector_type(4))) float f32x4;
typedef __attribute__((ext_vector_type(4))) unsigned short u16x4;

__device__ __forceinline__ unsigned short f2bf(float x) {
  union { float f; unsigned u; } v; v.f = x;
  unsigned r = v.u + 0x7fffu + ((v.u >> 16) & 1u);   // RNE
  return (unsigned short)(r >> 16);
}

__device__ __forceinline__ unsigned pack_bf2(float a, float b) {
  __hip_bfloat162 h = __float22bfloat162_rn(float2{a, b});
  union { __hip_bfloat162 h; unsigned u; } cv; cv.h = h; return cv.u;
}

__device__ __forceinline__ void gload_lds16(const void* g, void* l) {
  __builtin_amdgcn_global_load_lds(
      (const __attribute__((address_space(1))) unsigned int*)g,
      (__attribute__((address_space(3))) unsigned int*)l, 16, 0, 0);
}

#define MFMA16(a, b, c) __builtin_amdgcn_mfma_f32_16x16x32_bf16((a), (b), (c), 0, 0, 0)

// ---------------------------------------------------------------------------
// f32 -> bf16 flat convert (vectorized 4/lane)
// ---------------------------------------------------------------------------
__global__ __launch_bounds__(256) void conv_f32_bf16(
    const float4* __restrict__ src, u16x4* __restrict__ dst, int n4) {
  int i = blockIdx.x * 256 + threadIdx.x;
  int stride = gridDim.x * 256;
  for (; i < n4; i += stride) {
    float4 v = src[i];
    u16x4 o;
    o[0] = f2bf(v.x); o[1] = f2bf(v.y); o[2] = f2bf(v.z); o[3] = f2bf(v.w);
    dst[i] = o;
  }
}

// ---------------------------------------------------------------------------
// Weight transpose: src [H][D][DK] f32  ->  dst [H*DK][D] bf16  (B^T layout)
// ---------------------------------------------------------------------------
__global__ __launch_bounds__(256) void transpose_w(
    const float* __restrict__ src, unsigned short* __restrict__ dst,
    int D, int DK, int tilesD, int tilesK) {
  __shared__ float tile[64][65];
  int bid = blockIdx.x;
  int h = bid / (tilesD * tilesK);
  int rem = bid % (tilesD * tilesK);
  int dt = rem / tilesK, ktile = rem % tilesK;
  int d0 = dt * 64, k0 = ktile * 64;
  int tx = threadIdx.x & 63, ty = threadIdx.x >> 6;
  const float* s = src + (size_t)h * D * DK;
#pragma unroll
  for (int i = 0; i < 16; ++i) {
    int row = i * 4 + ty;
    tile[row][tx] = s[(size_t)(d0 + row) * DK + k0 + tx];
  }
  __syncthreads();
  unsigned short* dd = dst + (size_t)h * DK * D;
#pragma unroll
  for (int i = 0; i < 16; ++i) {
    int kk = i * 4 + ty;
    dd[(size_t)(k0 + kk) * D + d0 + tx] = f2bf(tile[tx][kk]);
  }
}

// ---------------------------------------------------------------------------
// GEMM: C[m][n] = sum_k A[m][k] * Bt[n][k],  K = 1024, bf16 in, tile 128x128
// mode 0: C f32 [M][1024]
// mode 1: C bf16 per-head [B,H,T,64]   (row = b*T+t, col = h*64+k)
// mode 2: C bf16 VhT [B,H,64,T]        (row = h*64+v, col = b*T+t)
// ---------------------------------------------------------------------------
__global__ __launch_bounds__(256) void gemm_bt(
    const unsigned short* __restrict__ A, const unsigned short* __restrict__ Bt,
    void* __restrict__ C, int nTilesN, int mode, float scale) {
  __shared__ unsigned short As[128 * 64];
  __shared__ unsigned short Bs[128 * 64];
  const int bid = blockIdx.x;
  const int bm = bid / nTilesN, bn = bid % nTilesN;
  const int m0 = bm * 128, n0 = bn * 128;
  const int tid = threadIdx.x;
  const int wave = tid >> 6, lane = tid & 63;
  const int wr = wave >> 1, wc = wave & 1;

  f32x4 acc[4][4];
#pragma unroll
  for (int m = 0; m < 4; ++m)
#pragma unroll
    for (int n = 0; n < 4; ++n) acc[m][n] = 0.f;

  const int soff = wave * 1024 + lane * 16;
  const char* Afr = (const char*)As + (wr * 64 + (lane & 15)) * 128 + (lane >> 4) * 16;
  const char* Bfr = (const char*)Bs + (wc * 64 + (lane & 15)) * 128 + (lane >> 4) * 16;

  for (int kt = 0; kt < 16; ++kt) {
    __syncthreads();
#pragma unroll
    for (int i = 0; i < 4; ++i) {
      int o2 = i * 4096 + soff;
      int row = o2 >> 7, colb = o2 & 127;
      gload_lds16((const char*)(A + (size_t)(m0 + row) * 1024 + kt * 64) + colb,
                  (char*)As + i * 4096 + wave * 1024);
      gload_lds16((const char*)(Bt + (size_t)(n0 + row) * 1024 + kt * 64) + colb,
                  (char*)Bs + i * 4096 + wave * 1024);
    }
    __syncthreads();
#pragma unroll
    for (int kk = 0; kk < 2; ++kk) {
      bf16x8 af[4], bf[4];
#pragma unroll
      for (int m = 0; m < 4; ++m) af[m] = *(const bf16x8*)(Afr + m * 2048 + kk * 64);
#pragma unroll
      for (int n = 0; n < 4; ++n) bf[n] = *(const bf16x8*)(Bfr + n * 2048 + kk * 64);
#pragma unroll
      for (int m = 0; m < 4; ++m)
#pragma unroll
        for (int n = 0; n < 4; ++n) acc[m][n] = MFMA16(af[m], bf[n], acc[m][n]);
    }
  }

  const int rbase = m0 + wr * 64 + ((lane >> 4) << 2);
  const int cbase = n0 + wc * 64 + (lane & 15);
#pragma unroll
  for (int m = 0; m < 4; ++m)
#pragma unroll
    for (int n = 0; n < 4; ++n)
#pragma unroll
      for (int r = 0; r < 4; ++r) {
        int row = rbase + m * 16 + r;
        int col = cbase + n * 16;
        float v = acc[m][n][r] * scale;
        if (mode == 0) {
          ((float*)C)[(size_t)row * 1024 + col] = v;
        } else if (mode == 1) {
          int b = row >> 11, t = row & 2047, h = col >> 6, k = col & 63;
          ((unsigned short*)C)[(((size_t)(b * H_ + h) * T_) + t) * 64 + k] = f2bf(v);
        } else {
          int h = row >> 6, vv = row & 63, b = col >> 11, t = col & 2047;
          ((unsigned short*)C)[(((size_t)(b * H_ + h) * 64) + vv) * T_ + t] = f2bf(v);
        }
      }
}

// ---------------------------------------------------------------------------
// Flash attention (causal), v4: heavy+light q-tile pairing for UNIFORM work.
// One block = (b, h, q-tile pair {31-p, p}); 4 waves, each wave owns 16 rows
// of each tile (frag j=0 -> heavy tile 31-p, j=1 -> light tile p). The light
// tile's KV range (kt<=p) is a subset of the heavy's (kt<=31-p), so ONE
// staged K/V stream (double-buffered, prefetched, XOR-swizzled via
// pre-swizzled global source) serves both. Per-block compute = 33 tile-units
// uniformly -> no causal tail. LDS 40KB -> 4 blocks/CU.
// Swapped QK^T -> lane-local softmax; defer-max (T13); Qh pre-scaled by
// log2(e)/8 -> pure exp2.
// ---------------------------------------------------------------------------
__global__ __launch_bounds__(256) void attn_fwd(
    const unsigned short* __restrict__ Qh, const unsigned short* __restrict__ Kh,
    const unsigned short* __restrict__ VhT, unsigned short* __restrict__ Abuf) {
  __shared__ unsigned short Ks[2][64 * 64];   // [s][k], swizzled, 8KB each
  __shared__ unsigned short Vs[2][64 * 64];   // [v][s], swizzled, 8KB each
  __shared__ unsigned short Ps[4][16 * 64];   // per-wave P [q][s], swizzled, 8KB

  const int bid = blockIdx.x;
  const int p  = bid & 15;                   // pair index
  const int bh = bid >> 4;                   // b*H + h
  const int b = bh >> 4, h = bh & 15;
  const int tid = threadIdx.x;
  const int wave = tid >> 6, lane = tid & 63;
  const int lq = lane & 15;
  const int hi = lane >> 4;
  const int nkt = 32 - p;                    // heavy tile KV count

  int q0[2];
  q0[0] = (31 - p) * 64 + wave * 16;         // heavy
  q0[1] = p * 64 + wave * 16;                // light

  const char* Kbase = (const char*)(Kh + (size_t)bh * T_ * 64);
  const char* Vbase = (const char*)(VhT + (size_t)bh * 64 * T_);

  // staging geometry: linear LDS dest, inverse-swizzled global source col
  int srow[2], scol[2], sdst[2];
#pragma unroll
  for (int i = 0; i < 2; ++i) {
    int o = i * 4096 + wave * 1024 + lane * 16;
    srow[i] = o >> 7;
    scol[i] = (o & 127) ^ ((srow[i] & 7) << 4);
    sdst[i] = i * 4096 + wave * 1024;        // wave-uniform dest (HW adds lane*16)
  }

  // Q fragments per tile
  bf16x8 qf[2][2];
#pragma unroll
  for (int j = 0; j < 2; ++j) {
    const unsigned short* qp = Qh + ((size_t)bh * T_ + q0[j] + lq) * 64 + hi * 8;
    qf[j][0] = *(const bf16x8*)qp;
    qf[j][1] = *(const bf16x8*)(qp + 32);
  }

  f32x4 o[2][4];
#pragma unroll
  for (int j = 0; j < 2; ++j)
#pragma unroll
    for (int n = 0; n < 4; ++n) o[j][n] = 0.f;
  float m_run[2] = {-1e30f, -1e30f}, l_run[2] = {0.f, 0.f};

  const int pswz = (lq & 7) << 4;
  char* pw = (char*)&Ps[wave][0] + lq * 128;

  auto stage = [&](int buf, int kt) {
#pragma unroll
    for (int i = 0; i < 2; ++i) {
      gload_lds16(Kbase + (size_t)(kt * 64 + srow[i]) * 128 + scol[i],
                  (char*)Ks[buf] + sdst[i]);
      gload_lds16(Vbase + (size_t)srow[i] * (T_ * 2) + kt * 128 + scol[i],
                  (char*)Vs[buf] + sdst[i]);
    }
  };

  // prologue: stage tile 0
  stage(0, 0);
  asm volatile("s_waitcnt vmcnt(0)" ::: "memory");
  __builtin_amdgcn_s_barrier();

  int cur = 0;
  for (int kt = 0; kt < nkt; ++kt) {
    const int s0 = kt * 64;
    if (kt + 1 < nkt) stage(cur ^ 1, kt + 1);   // prefetch overlaps compute

    const char* KsB = (const char*)Ks[cur];
    const char* VsB = (const char*)Vs[cur];

#pragma unroll
    for (int j = 0; j < 2; ++j) {
      if (j == 1 && kt > p) continue;          // light tile done (block-uniform)

      // ---- QK^T: S^T[s][q] ----
      f32x4 sc[4];
#pragma unroll
      for (int c = 0; c < 4; ++c) {
        int r = c * 16 + lq;
        const char* kb = KsB + r * 128;
        int sw = (r & 7) << 4;
        bf16x8 ka0 = *(const bf16x8*)(kb + ((hi * 16) ^ sw));
        bf16x8 ka1 = *(const bf16x8*)(kb + ((64 + hi * 16) ^ sw));
        f32x4 z = 0.f;
        z = MFMA16(ka0, qf[j][0], z);
        sc[c] = MFMA16(ka1, qf[j][1], z);
      }

      if (s0 + 63 > q0[j]) {                   // diagonal tile: element mask
        int qg = q0[j] + lq;
#pragma unroll
        for (int c = 0; c < 4; ++c)
#pragma unroll
          for (int r = 0; r < 4; ++r) {
            int sg = s0 + c * 16 + hi * 4 + r;
            if (sg > qg) sc[c][r] = -1e30f;
          }
      }

      // ---- online softmax (log2 domain), row q = lane&15 lane-local ----
      float pmax = sc[0][0];
#pragma unroll
      for (int c = 0; c < 4; ++c)
#pragma unroll
        for (int r = 0; r < 4; ++r) pmax = fmaxf(pmax, sc[c][r]);
      pmax = fmaxf(pmax, __shfl_xor(pmax, 16));
      pmax = fmaxf(pmax, __shfl_xor(pmax, 32));

      if (!__all(pmax - m_run[j] <= 8.f)) {    // defer-max (T13)
        float mnew = fmaxf(m_run[j], pmax);
        float corr = __builtin_amdgcn_exp2f(m_run[j] - mnew);
        float cr[4];
#pragma unroll
        for (int r = 0; r < 4; ++r) cr[r] = __shfl(corr, hi * 4 + r);
#pragma unroll
        for (int n = 0; n < 4; ++n)
#pragma unroll
          for (int r = 0; r < 4; ++r) o[j][n][r] *= cr[r];
        l_run[j] *= corr;
        m_run[j] = mnew;
      }

      float psum = 0.f;
#pragma unroll
      for (int c = 0; c < 4; ++c)
#pragma unroll
        for (int r = 0; r < 4; ++r) {
          float pv = __builtin_amdgcn_exp2f(sc[c][r] - m_run[j]);
          sc[c][r] = pv;
          psum += pv;
        }
      psum += __shfl_xor(psum, 16);
      psum += __shfl_xor(psum, 32);
      l_run[j] += psum;

      // ---- P -> wave-private LDS [q][s], swizzled ----
#pragma unroll
      for (int c = 0; c < 4; ++c) {
        uint2 pk;
        pk.x = pack_bf2(sc[c][0], sc[c][1]);
        pk.y = pack_bf2(sc[c][2], sc[c][3]);
        *(uint2*)(pw + ((c * 32 + hi * 8) ^ pswz)) = pk;
      }

      // ---- O += P @ V ----
#pragma unroll
      for (int ks = 0; ks < 2; ++ks) {
        bf16x8 pa = *(const bf16x8*)(pw + ((ks * 64 + hi * 16) ^ pswz));
#pragma unroll
        for (int n = 0; n < 4; ++n) {
          int rv = n * 16 + lq;
          bf16x8 vb = *(const bf16x8*)(VsB + rv * 128 +
                                       ((ks * 64 + hi * 16) ^ ((rv & 7) << 4)));
          o[j][n] = MFMA16(pa, vb, o[j][n]);
        }
      }
    }

    // tile boundary: drain prefetch, sync all waves
    asm volatile("s_waitcnt vmcnt(0)" ::: "memory");
    __builtin_amdgcn_s_barrier();
    cur ^= 1;
  }

  // finalize: divide by l, write A [b*T+t][h*64+v] bf16
#pragma unroll
  for (int j = 0; j < 2; ++j) {
    float inv[4];
#pragma unroll
    for (int r = 0; r < 4; ++r)
      inv[r] = 1.0f / __shfl(l_run[j], hi * 4 + r);
#pragma unroll
    for (int r = 0; r < 4; ++r) {
      int t = q0[j] + hi * 4 + r;
      size_t base = ((size_t)b * T_ + t) * 1024 + h * 64 + lq;
#pragma unroll
      for (int n = 0; n < 4; ++n)
        Abuf[base + n * 16] = f2bf(o[j][n][r] * inv[r]);
    }
  }
}

// ---------------------------------------------------------------------------
extern "C" void kernel_launch(void* const* d_in, const int* in_sizes, int n_in,
                              void* d_out, int out_size, void* d_ws, size_t ws_size,
                              hipStream_t stream) {
  (void)in_sizes; (void)n_in; (void)out_size; (void)ws_size;
  const float* Q  = (const float*)d_in[0];
  const float* K  = (const float*)d_in[1];
  const float* V  = (const float*)d_in[2];
  const float* WQ = (const float*)d_in[3];
  const float* WK = (const float*)d_in[4];
  const float* WV = (const float*)d_in[5];
  const float* WO = (const float*)d_in[6];
  float* out = (float*)d_out;
  char* ws = (char*)d_ws;

  const size_t SZ_ACT = (size_t)8192 * 1024 * 2;  // 16.78 MB
  const size_t SZ_W   = (size_t)1024 * 1024 * 2;  //  2.10 MB
  unsigned short* Qbf = (unsigned short*)(ws);
  unsigned short* Kbf = (unsigned short*)(ws + SZ_ACT);
  unsigned short* Vbf = (unsigned short*)(ws + 2 * SZ_ACT);
  unsigned short* WqT = (unsigned short*)(ws + 3 * SZ_ACT);
  unsigned short* WkT = (unsigned short*)(ws + 3 * SZ_ACT + SZ_W);
  unsigned short* WvT = (unsigned short*)(ws + 3 * SZ_ACT + 2 * SZ_W);
  unsigned short* WOt = (unsigned short*)(ws + 3 * SZ_ACT + 3 * SZ_W);
  unsigned short* Qh  = (unsigned short*)(ws + 3 * SZ_ACT + 4 * SZ_W);
  unsigned short* Kh  = (unsigned short*)(ws + 4 * SZ_ACT + 4 * SZ_W);
  unsigned short* VhT = (unsigned short*)(ws + 5 * SZ_ACT + 4 * SZ_W);
  unsigned short* Abuf = Qbf;  // Qbf dead after Q projection

  // 1) convert activations to bf16
  conv_f32_bf16<<<2048, 256, 0, stream>>>((const float4*)Q, (u16x4*)Qbf, 2097152);
  conv_f32_bf16<<<2048, 256, 0, stream>>>((const float4*)K, (u16x4*)Kbf, 2097152);
  conv_f32_bf16<<<2048, 256, 0, stream>>>((const float4*)V, (u16x4*)Vbf, 2097152);

  // 2) transpose weights to B^T bf16
  transpose_w<<<256, 256, 0, stream>>>(WQ, WqT, 1024, 64, 16, 1);
  transpose_w<<<256, 256, 0, stream>>>(WK, WkT, 1024, 64, 16, 1);
  transpose_w<<<256, 256, 0, stream>>>(WV, WvT, 1024, 64, 16, 1);
  transpose_w<<<256, 256, 0, stream>>>(WO, WOt, 1024, 1024, 16, 16);

  // 3) projections (Q scaled by log2(e)/sqrt(dk))
  const float qscale = 1.4426950408889634f / 8.0f;
  gemm_bt<<<512, 256, 0, stream>>>(Qbf, WqT, Qh, 8, 1, qscale);   // M=8192,N=1024
  gemm_bt<<<512, 256, 0, stream>>>(Kbf, WkT, Kh, 8, 1, 1.0f);
  gemm_bt<<<512, 256, 0, stream>>>(WvT, Vbf, VhT, 64, 2, 1.0f);   // M=1024,N=8192 -> VhT

  // 4) causal flash attention (paired q-tiles, uniform work)
  attn_fwd<<<1024, 256, 0, stream>>>(Qh, Kh, VhT, Abuf);

  // 5) output projection -> f32
  gemm_bt<<<512, 256, 0, stream>>>(Abuf, WOt, out, 8, 0, 1.0f);
}

// Round 5
// 230.378 us; speedup vs baseline: 2.6873x; 1.1460x over previous
//
#include <hip/hip_runtime.h>
#include <hip/hip_bf16.h>

// Problem constants (fixed)
#define B_ 4
#define T_ 2048
#define D_ 1024
#define H_ 16
// DK = DV = 64

typedef __attribute__((ext_vector_type(8))) short bf16x8;
typedef __attribute__((ext_vector_type(4))) float f32x4;
typedef __attribute__((ext_vector_type(4))) unsigned short u16x4;

__device__ __forceinline__ unsigned short f2bf(float x) {
  union { float f; unsigned u; } v; v.f = x;
  unsigned r = v.u + 0x7fffu + ((v.u >> 16) & 1u);   // RNE
  return (unsigned short)(r >> 16);
}

__device__ __forceinline__ unsigned pack_bf2(float a, float b) {
  __hip_bfloat162 h = __float22bfloat162_rn(float2{a, b});
  union { __hip_bfloat162 h; unsigned u; } cv; cv.h = h; return cv.u;
}

__device__ __forceinline__ void gload_lds16(const void* g, void* l) {
  __builtin_amdgcn_global_load_lds(
      (const __attribute__((address_space(1))) unsigned int*)g,
      (__attribute__((address_space(3))) unsigned int*)l, 16, 0, 0);
}

#define MFMA16(a, b, c) __builtin_amdgcn_mfma_f32_16x16x32_bf16((a), (b), (c), 0, 0, 0)

// ---------------------------------------------------------------------------
// f32 -> bf16 convert, all three activations in ONE dispatch (3072 blocks)
// ---------------------------------------------------------------------------
__global__ __launch_bounds__(256) void conv3(
    const float4* __restrict__ Q, const float4* __restrict__ K,
    const float4* __restrict__ V, u16x4* __restrict__ Qb,
    u16x4* __restrict__ Kb, u16x4* __restrict__ Vb) {
  const int seg = blockIdx.x >> 10;          // 1024 blocks per tensor
  const int sb  = blockIdx.x & 1023;
  const float4* s = (seg == 0) ? Q : (seg == 1) ? K : V;
  u16x4* d       = (seg == 0) ? Qb : (seg == 1) ? Kb : Vb;
  int i = sb * 256 + threadIdx.x;
#pragma unroll
  for (int it = 0; it < 8; ++it, i += 262144) {   // 1024*256 stride, n4=2097152
    float4 v = s[i];
    u16x4 o;
    o[0] = f2bf(v.x); o[1] = f2bf(v.y); o[2] = f2bf(v.z); o[3] = f2bf(v.w);
    d[i] = o;
  }
}

// ---------------------------------------------------------------------------
// Weight transposes, all four in ONE dispatch (1024 blocks).
// seg 0..2: [16][1024][64] f32 -> [16*64][1024] bf16 (256 blocks each)
// seg 3:    [1024][1024] f32 -> [1024][1024] bf16 transposed (256 blocks)
// ---------------------------------------------------------------------------
__global__ __launch_bounds__(256) void trans4(
    const float* __restrict__ WQ, const float* __restrict__ WK,
    const float* __restrict__ WV, const float* __restrict__ WO,
    unsigned short* __restrict__ WqT, unsigned short* __restrict__ WkT,
    unsigned short* __restrict__ WvT, unsigned short* __restrict__ WOt) {
  __shared__ float tile[64][65];
  const int seg = blockIdx.x >> 8;
  const int sub = blockIdx.x & 255;
  const float* src = (seg == 0) ? WQ : (seg == 1) ? WK : (seg == 2) ? WV : WO;
  unsigned short* dst = (seg == 0) ? WqT : (seg == 1) ? WkT : (seg == 2) ? WvT : WOt;
  const int DK = (seg == 3) ? 1024 : 64;
  int h, dt, ktile;
  if (seg == 3) { h = 0; dt = sub >> 4; ktile = sub & 15; }
  else          { h = sub >> 4; dt = sub & 15; ktile = 0; }
  const int d0 = dt * 64, k0 = ktile * 64;
  const int tx = threadIdx.x & 63, ty = threadIdx.x >> 6;
  const float* s = src + (size_t)h * 1024 * DK;
#pragma unroll
  for (int i = 0; i < 16; ++i) {
    int row = i * 4 + ty;
    tile[row][tx] = s[(size_t)(d0 + row) * DK + k0 + tx];
  }
  __syncthreads();
  unsigned short* dd = dst + (size_t)h * DK * 1024;
#pragma unroll
  for (int i = 0; i < 16; ++i) {
    int kk = i * 4 + ty;
    dd[(size_t)(k0 + kk) * 1024 + d0 + tx] = f2bf(tile[tx][kk]);
  }
}

// ---------------------------------------------------------------------------
// GEMM body: C[m][n] = sum_k A[m][k] * Bt[n][k], K=1024, bf16 in, tile 128x128
// mode 0: C f32 [M][1024]
// mode 1: C bf16 per-head [B,H,T,64]   (row = b*T+t, col = h*64+k)
// mode 2: C bf16 VhT [B,H,64,T]        (row = h*64+v, col = b*T+t)
// ---------------------------------------------------------------------------
__device__ __forceinline__ void gemm_body(
    const unsigned short* __restrict__ A, const unsigned short* __restrict__ Bt,
    void* __restrict__ C, int bid, int nTilesN, int mode, float scale) {
  __shared__ unsigned short As[128 * 64];
  __shared__ unsigned short Bs[128 * 64];
  const int bm = bid / nTilesN, bn = bid % nTilesN;
  const int m0 = bm * 128, n0 = bn * 128;
  const int tid = threadIdx.x;
  const int wave = tid >> 6, lane = tid & 63;
  const int wr = wave >> 1, wc = wave & 1;

  f32x4 acc[4][4];
#pragma unroll
  for (int m = 0; m < 4; ++m)
#pragma unroll
    for (int n = 0; n < 4; ++n) acc[m][n] = 0.f;

  const int soff = wave * 1024 + lane * 16;
  const char* Afr = (const char*)As + (wr * 64 + (lane & 15)) * 128 + (lane >> 4) * 16;
  const char* Bfr = (const char*)Bs + (wc * 64 + (lane & 15)) * 128 + (lane >> 4) * 16;

  for (int kt = 0; kt < 16; ++kt) {
    __syncthreads();
#pragma unroll
    for (int i = 0; i < 4; ++i) {
      int o2 = i * 4096 + soff;
      int row = o2 >> 7, colb = o2 & 127;
      gload_lds16((const char*)(A + (size_t)(m0 + row) * 1024 + kt * 64) + colb,
                  (char*)As + i * 4096 + wave * 1024);
      gload_lds16((const char*)(Bt + (size_t)(n0 + row) * 1024 + kt * 64) + colb,
                  (char*)Bs + i * 4096 + wave * 1024);
    }
    __syncthreads();
#pragma unroll
    for (int kk = 0; kk < 2; ++kk) {
      bf16x8 af[4], bf[4];
#pragma unroll
      for (int m = 0; m < 4; ++m) af[m] = *(const bf16x8*)(Afr + m * 2048 + kk * 64);
#pragma unroll
      for (int n = 0; n < 4; ++n) bf[n] = *(const bf16x8*)(Bfr + n * 2048 + kk * 64);
#pragma unroll
      for (int m = 0; m < 4; ++m)
#pragma unroll
        for (int n = 0; n < 4; ++n) acc[m][n] = MFMA16(af[m], bf[n], acc[m][n]);
    }
  }

  const int rbase = m0 + wr * 64 + ((lane >> 4) << 2);
  const int cbase = n0 + wc * 64 + (lane & 15);
#pragma unroll
  for (int m = 0; m < 4; ++m)
#pragma unroll
    for (int n = 0; n < 4; ++n)
#pragma unroll
      for (int r = 0; r < 4; ++r) {
        int row = rbase + m * 16 + r;
        int col = cbase + n * 16;
        float v = acc[m][n][r] * scale;
        if (mode == 0) {
          ((float*)C)[(size_t)row * 1024 + col] = v;
        } else if (mode == 1) {
          int b = row >> 11, t = row & 2047, h = col >> 6, k = col & 63;
          ((unsigned short*)C)[(((size_t)(b * H_ + h) * T_) + t) * 64 + k] = f2bf(v);
        } else {
          int h = row >> 6, vv = row & 63, b = col >> 11, t = col & 2047;
          ((unsigned short*)C)[(((size_t)(b * H_ + h) * 64) + vv) * T_ + t] = f2bf(v);
        }
      }
}

// All three projection GEMMs in ONE dispatch (1536 blocks), XCD-swizzled so
// blocks sharing an A-panel co-locate on one XCD's L2.
__global__ __launch_bounds__(256) void gemm_proj3(
    const unsigned short* __restrict__ Qbf, const unsigned short* __restrict__ WqT,
    unsigned short* __restrict__ Qh,
    const unsigned short* __restrict__ Kbf, const unsigned short* __restrict__ WkT,
    unsigned short* __restrict__ Kh,
    const unsigned short* __restrict__ WvT, const unsigned short* __restrict__ Vbf,
    unsigned short* __restrict__ VhT, float qscale) {
  const int bid = blockIdx.x;
  const int wid = (bid & 7) * 192 + (bid >> 3);   // 1536/8 = 192, bijective
  const int seg = wid / 512, sub = wid % 512;
  const unsigned short* A  = (seg == 0) ? Qbf : (seg == 1) ? Kbf : WvT;
  const unsigned short* Bt = (seg == 0) ? WqT : (seg == 1) ? WkT : Vbf;
  void* C = (seg == 0) ? (void*)Qh : (seg == 1) ? (void*)Kh : (void*)VhT;
  gemm_body(A, Bt, C, sub, (seg == 2) ? 64 : 8, (seg == 2) ? 2 : 1,
            (seg == 0) ? qscale : 1.0f);
}

__global__ __launch_bounds__(256) void gemm_out(
    const unsigned short* __restrict__ A, const unsigned short* __restrict__ Bt,
    float* __restrict__ C) {
  const int bid = blockIdx.x;
  const int wid = (bid & 7) * 64 + (bid >> 3);    // 512/8 = 64, bijective
  gemm_body(A, Bt, C, wid, 8, 0, 1.0f);
}

// ---------------------------------------------------------------------------
// Flash attention (causal), v5: v4 structure + XCD swizzle + setprio.
// One block = (b, h, q-tile pair {31-p, p}); ONE staged K/V stream serves
// both tiles (light subset of heavy). Double-buffered, prefetched,
// XOR-swizzled via pre-swizzled global source. 33 tile-units/block uniform.
// XCD swizzle: 16 same-bh blocks contiguous on one XCD -> K/V tiles read by
// all 16 within a short window -> L2-hit prefetch drains.
// ---------------------------------------------------------------------------
__global__ __launch_bounds__(256) void attn_fwd(
    const unsigned short* __restrict__ Qh, const unsigned short* __restrict__ Kh,
    const unsigned short* __restrict__ VhT, unsigned short* __restrict__ Abuf) {
  __shared__ unsigned short Ks[2][64 * 64];   // [s][k], swizzled, 8KB each
  __shared__ unsigned short Vs[2][64 * 64];   // [v][s], swizzled, 8KB each
  __shared__ unsigned short Ps[4][16 * 64];   // per-wave P [q][s], swizzled, 8KB

  const int bid = blockIdx.x;
  const int wid = ((bid & 7) << 7) | (bid >> 3);  // XCD swizzle (1024 % 8 == 0)
  const int p  = wid & 15;                   // pair index
  const int bh = wid >> 4;                   // b*H + h
  const int b = bh >> 4, h = bh & 15;
  const int tid = threadIdx.x;
  const int wave = tid >> 6, lane = tid & 63;
  const int lq = lane & 15;
  const int hi = lane >> 4;
  const int nkt = 32 - p;                    // heavy tile KV count

  int q0[2];
  q0[0] = (31 - p) * 64 + wave * 16;         // heavy
  q0[1] = p * 64 + wave * 16;                // light

  const char* Kbase = (const char*)(Kh + (size_t)bh * T_ * 64);
  const char* Vbase = (const char*)(VhT + (size_t)bh * 64 * T_);

  // staging geometry: linear LDS dest, inverse-swizzled global source col
  int srow[2], scol[2], sdst[2];
#pragma unroll
  for (int i = 0; i < 2; ++i) {
    int o = i * 4096 + wave * 1024 + lane * 16;
    srow[i] = o >> 7;
    scol[i] = (o & 127) ^ ((srow[i] & 7) << 4);
    sdst[i] = i * 4096 + wave * 1024;        // wave-uniform dest (HW adds lane*16)
  }

  // Q fragments per tile
  bf16x8 qf[2][2];
#pragma unroll
  for (int j = 0; j < 2; ++j) {
    const unsigned short* qp = Qh + ((size_t)bh * T_ + q0[j] + lq) * 64 + hi * 8;
    qf[j][0] = *(const bf16x8*)qp;
    qf[j][1] = *(const bf16x8*)(qp + 32);
  }

  f32x4 o[2][4];
#pragma unroll
  for (int j = 0; j < 2; ++j)
#pragma unroll
    for (int n = 0; n < 4; ++n) o[j][n] = 0.f;
  float m_run[2] = {-1e30f, -1e30f}, l_run[2] = {0.f, 0.f};

  const int pswz = (lq & 7) << 4;
  char* pw = (char*)&Ps[wave][0] + lq * 128;

  auto stage = [&](int buf, int kt) {
#pragma unroll
    for (int i = 0; i < 2; ++i) {
      gload_lds16(Kbase + (size_t)(kt * 64 + srow[i]) * 128 + scol[i],
                  (char*)Ks[buf] + sdst[i]);
      gload_lds16(Vbase + (size_t)srow[i] * (T_ * 2) + kt * 128 + scol[i],
                  (char*)Vs[buf] + sdst[i]);
    }
  };

  // prologue: stage tile 0
  stage(0, 0);
  asm volatile("s_waitcnt vmcnt(0)" ::: "memory");
  __builtin_amdgcn_s_barrier();

  int cur = 0;
  for (int kt = 0; kt < nkt; ++kt) {
    const int s0 = kt * 64;
    if (kt + 1 < nkt) stage(cur ^ 1, kt + 1);   // prefetch overlaps compute

    const char* KsB = (const char*)Ks[cur];
    const char* VsB = (const char*)Vs[cur];

#pragma unroll
    for (int j = 0; j < 2; ++j) {
      if (j == 1 && kt > p) continue;          // light tile done (block-uniform)

      // ---- QK^T: S^T[s][q] ----
      f32x4 sc[4];
      __builtin_amdgcn_s_setprio(1);
#pragma unroll
      for (int c = 0; c < 4; ++c) {
        int r = c * 16 + lq;
        const char* kb = KsB + r * 128;
        int sw = (r & 7) << 4;
        bf16x8 ka0 = *(const bf16x8*)(kb + ((hi * 16) ^ sw));
        bf16x8 ka1 = *(const bf16x8*)(kb + ((64 + hi * 16) ^ sw));
        f32x4 z = 0.f;
        z = MFMA16(ka0, qf[j][0], z);
        sc[c] = MFMA16(ka1, qf[j][1], z);
      }
      __builtin_amdgcn_s_setprio(0);

      if (s0 + 63 > q0[j]) {                   // diagonal tile: element mask
        int qg = q0[j] + lq;
#pragma unroll
        for (int c = 0; c < 4; ++c)
#pragma unroll
          for (int r = 0; r < 4; ++r) {
            int sg = s0 + c * 16 + hi * 4 + r;
            if (sg > qg) sc[c][r] = -1e30f;
          }
      }

      // ---- online softmax (log2 domain), row q = lane&15 lane-local ----
      float pmax = sc[0][0];
#pragma unroll
      for (int c = 0; c < 4; ++c)
#pragma unroll
        for (int r = 0; r < 4; ++r) pmax = fmaxf(pmax, sc[c][r]);
      pmax = fmaxf(pmax, __shfl_xor(pmax, 16));
      pmax = fmaxf(pmax, __shfl_xor(pmax, 32));

      if (!__all(pmax - m_run[j] <= 8.f)) {    // defer-max (T13)
        float mnew = fmaxf(m_run[j], pmax);
        float corr = __builtin_amdgcn_exp2f(m_run[j] - mnew);
        float cr[4];
#pragma unroll
        for (int r = 0; r < 4; ++r) cr[r] = __shfl(corr, hi * 4 + r);
#pragma unroll
        for (int n = 0; n < 4; ++n)
#pragma unroll
          for (int r = 0; r < 4; ++r) o[j][n][r] *= cr[r];
        l_run[j] *= corr;
        m_run[j] = mnew;
      }

      float psum = 0.f;
#pragma unroll
      for (int c = 0; c < 4; ++c)
#pragma unroll
        for (int r = 0; r < 4; ++r) {
          float pv = __builtin_amdgcn_exp2f(sc[c][r] - m_run[j]);
          sc[c][r] = pv;
          psum += pv;
        }
      psum += __shfl_xor(psum, 16);
      psum += __shfl_xor(psum, 32);
      l_run[j] += psum;

      // ---- P -> wave-private LDS [q][s], swizzled ----
#pragma unroll
      for (int c = 0; c < 4; ++c) {
        uint2 pk;
        pk.x = pack_bf2(sc[c][0], sc[c][1]);
        pk.y = pack_bf2(sc[c][2], sc[c][3]);
        *(uint2*)(pw + ((c * 32 + hi * 8) ^ pswz)) = pk;
      }

      // ---- O += P @ V ----
      __builtin_amdgcn_s_setprio(1);
#pragma unroll
      for (int ks = 0; ks < 2; ++ks) {
        bf16x8 pa = *(const bf16x8*)(pw + ((ks * 64 + hi * 16) ^ pswz));
#pragma unroll
        for (int n = 0; n < 4; ++n) {
          int rv = n * 16 + lq;
          bf16x8 vb = *(const bf16x8*)(VsB + rv * 128 +
                                       ((ks * 64 + hi * 16) ^ ((rv & 7) << 4)));
          o[j][n] = MFMA16(pa, vb, o[j][n]);
        }
      }
      __builtin_amdgcn_s_setprio(0);
    }

    // tile boundary: drain prefetch, sync all waves
    asm volatile("s_waitcnt vmcnt(0)" ::: "memory");
    __builtin_amdgcn_s_barrier();
    cur ^= 1;
  }

  // finalize: divide by l, write A [b*T+t][h*64+v] bf16
#pragma unroll
  for (int j = 0; j < 2; ++j) {
    float inv[4];
#pragma unroll
    for (int r = 0; r < 4; ++r)
      inv[r] = 1.0f / __shfl(l_run[j], hi * 4 + r);
#pragma unroll
    for (int r = 0; r < 4; ++r) {
      int t = q0[j] + hi * 4 + r;
      size_t base = ((size_t)b * T_ + t) * 1024 + h * 64 + lq;
#pragma unroll
      for (int n = 0; n < 4; ++n)
        Abuf[base + n * 16] = f2bf(o[j][n][r] * inv[r]);
    }
  }
}

// ---------------------------------------------------------------------------
extern "C" void kernel_launch(void* const* d_in, const int* in_sizes, int n_in,
                              void* d_out, int out_size, void* d_ws, size_t ws_size,
                              hipStream_t stream) {
  (void)in_sizes; (void)n_in; (void)out_size; (void)ws_size;
  const float* Q  = (const float*)d_in[0];
  const float* K  = (const float*)d_in[1];
  const float* V  = (const float*)d_in[2];
  const float* WQ = (const float*)d_in[3];
  const float* WK = (const float*)d_in[4];
  const float* WV = (const float*)d_in[5];
  const float* WO = (const float*)d_in[6];
  float* out = (float*)d_out;
  char* ws = (char*)d_ws;

  const size_t SZ_ACT = (size_t)8192 * 1024 * 2;  // 16.78 MB
  const size_t SZ_W   = (size_t)1024 * 1024 * 2;  //  2.10 MB
  unsigned short* Qbf = (unsigned short*)(ws);
  unsigned short* Kbf = (unsigned short*)(ws + SZ_ACT);
  unsigned short* Vbf = (unsigned short*)(ws + 2 * SZ_ACT);
  unsigned short* WqT = (unsigned short*)(ws + 3 * SZ_ACT);
  unsigned short* WkT = (unsigned short*)(ws + 3 * SZ_ACT + SZ_W);
  unsigned short* WvT = (unsigned short*)(ws + 3 * SZ_ACT + 2 * SZ_W);
  unsigned short* WOt = (unsigned short*)(ws + 3 * SZ_ACT + 3 * SZ_W);
  unsigned short* Qh  = (unsigned short*)(ws + 3 * SZ_ACT + 4 * SZ_W);
  unsigned short* Kh  = (unsigned short*)(ws + 4 * SZ_ACT + 4 * SZ_W);
  unsigned short* VhT = (unsigned short*)(ws + 5 * SZ_ACT + 4 * SZ_W);
  unsigned short* Abuf = Qbf;  // Qbf dead after Q projection

  // 1) convert activations to bf16 (one dispatch)
  conv3<<<3072, 256, 0, stream>>>((const float4*)Q, (const float4*)K,
                                  (const float4*)V, (u16x4*)Qbf, (u16x4*)Kbf,
                                  (u16x4*)Vbf);

  // 2) transpose weights to B^T bf16 (one dispatch)
  trans4<<<1024, 256, 0, stream>>>(WQ, WK, WV, WO, WqT, WkT, WvT, WOt);

  // 3) projections (one dispatch; Q scaled by log2(e)/sqrt(dk))
  const float qscale = 1.4426950408889634f / 8.0f;
  gemm_proj3<<<1536, 256, 0, stream>>>(Qbf, WqT, Qh, Kbf, WkT, Kh,
                                       WvT, Vbf, VhT, qscale);

  // 4) causal flash attention (paired q-tiles, XCD-swizzled, setprio)
  attn_fwd<<<1024, 256, 0, stream>>>(Qh, Kh, VhT, Abuf);

  // 5) output projection -> f32
  gemm_out<<<512, 256, 0, stream>>>(Abuf, WOt, out);
}

// Round 6
// 227.413 us; speedup vs baseline: 2.7223x; 1.0130x over previous
//
#include <hip/hip_runtime.h>
#include <hip/hip_bf16.h>

// Problem constants (fixed)
#define B_ 4
#define T_ 2048
#define D_ 1024
#define H_ 16
// DK = DV = 64

typedef __attribute__((ext_vector_type(8))) short bf16x8;
typedef __attribute__((ext_vector_type(4))) float f32x4;
typedef __attribute__((ext_vector_type(4))) unsigned short u16x4;
typedef __attribute__((ext_vector_type(4))) unsigned int u32x4;

__device__ __forceinline__ unsigned short f2bf(float x) {
  union { float f; unsigned u; } v; v.f = x;
  unsigned r = v.u + 0x7fffu + ((v.u >> 16) & 1u);   // RNE
  return (unsigned short)(r >> 16);
}

__device__ __forceinline__ unsigned pack_bf2(float a, float b) {
  __hip_bfloat162 h = __float22bfloat162_rn(float2{a, b});
  union { __hip_bfloat162 h; unsigned u; } cv; cv.h = h; return cv.u;
}

__device__ __forceinline__ void gload_lds16(const void* g, void* l) {
  __builtin_amdgcn_global_load_lds(
      (const __attribute__((address_space(1))) unsigned int*)g,
      (__attribute__((address_space(3))) unsigned int*)l, 16, 0, 0);
}

#define MFMA16(a, b, c) __builtin_amdgcn_mfma_f32_16x16x32_bf16((a), (b), (c), 0, 0, 0)

// ---------------------------------------------------------------------------
// Weight transposes, all four in ONE dispatch (1024 blocks).
// seg 0..2: [16][1024][64] f32 -> [16*64][1024] bf16 (256 blocks each)
// seg 3:    [1024][1024] f32 -> [1024][1024] bf16 transposed (256 blocks)
// ---------------------------------------------------------------------------
__global__ __launch_bounds__(256) void trans4(
    const float* __restrict__ WQ, const float* __restrict__ WK,
    const float* __restrict__ WV, const float* __restrict__ WO,
    unsigned short* __restrict__ WqT, unsigned short* __restrict__ WkT,
    unsigned short* __restrict__ WvT, unsigned short* __restrict__ WOt) {
  __shared__ float tile[64][65];
  const int seg = blockIdx.x >> 8;
  const int sub = blockIdx.x & 255;
  const float* src = (seg == 0) ? WQ : (seg == 1) ? WK : (seg == 2) ? WV : WO;
  unsigned short* dst = (seg == 0) ? WqT : (seg == 1) ? WkT : (seg == 2) ? WvT : WOt;
  const int DK = (seg == 3) ? 1024 : 64;
  int h, dt, ktile;
  if (seg == 3) { h = 0; dt = sub >> 4; ktile = sub & 15; }
  else          { h = sub >> 4; dt = sub & 15; ktile = 0; }
  const int d0 = dt * 64, k0 = ktile * 64;
  const int tx = threadIdx.x & 63, ty = threadIdx.x >> 6;
  const float* s = src + (size_t)h * 1024 * DK;
#pragma unroll
  for (int i = 0; i < 16; ++i) {
    int row = i * 4 + ty;
    tile[row][tx] = s[(size_t)(d0 + row) * DK + k0 + tx];
  }
  __syncthreads();
  unsigned short* dd = dst + (size_t)h * DK * 1024;
#pragma unroll
  for (int i = 0; i < 16; ++i) {
    int kk = i * 4 + ty;
    dd[(size_t)(k0 + kk) * 1024 + d0 + tx] = f2bf(tile[tx][kk]);
  }
}

// ---------------------------------------------------------------------------
// GEMM body: C[m][n] = sum_k A[m][k] * Bt[n][k], K=1024, tile 128x128.
// AF32/BF32: that operand is f32 in global, converted to bf16 during staging
// (reg-staged: 2x float4 load -> 4x cvt_pk -> ds_write_b128). bf16 operands
// stage via global_load_lds width-16.
// CMODE 0: C f32 [M][1024]
// CMODE 1: C bf16 per-head [B,H,T,64]   (row = b*T+t, col = h*64+k)
// CMODE 2: C bf16 VhT [B,H,64,T]        (row = h*64+v, col = b*T+t)
// ---------------------------------------------------------------------------
template <bool AF32, bool BF32, int CMODE>
__device__ __forceinline__ void gemm_body(
    const void* __restrict__ Ap, const void* __restrict__ Btp,
    void* __restrict__ C, int bid, int nTilesN, float scale) {
  __shared__ unsigned short As[128 * 64];
  __shared__ unsigned short Bs[128 * 64];
  const int bm = bid / nTilesN, bn = bid % nTilesN;
  const int m0 = bm * 128, n0 = bn * 128;
  const int tid = threadIdx.x;
  const int wave = tid >> 6, lane = tid & 63;
  const int wr = wave >> 1, wc = wave & 1;

  f32x4 acc[4][4];
#pragma unroll
  for (int m = 0; m < 4; ++m)
#pragma unroll
    for (int n = 0; n < 4; ++n) acc[m][n] = 0.f;

  const int soff = wave * 1024 + lane * 16;
  const char* Afr = (const char*)As + (wr * 64 + (lane & 15)) * 128 + (lane >> 4) * 16;
  const char* Bfr = (const char*)Bs + (wc * 64 + (lane & 15)) * 128 + (lane >> 4) * 16;

  for (int kt = 0; kt < 16; ++kt) {
    __syncthreads();
#pragma unroll
    for (int i = 0; i < 4; ++i) {
      int o2 = i * 4096 + soff;
      int row = o2 >> 7, colb = o2 & 127;
      if constexpr (AF32) {
        const float* src = (const float*)Ap + (size_t)(m0 + row) * 1024 + kt * 64 + (colb >> 1);
        float4 f0 = *(const float4*)src;
        float4 f1 = *(const float4*)(src + 4);
        u32x4 w;
        w[0] = pack_bf2(f0.x, f0.y); w[1] = pack_bf2(f0.z, f0.w);
        w[2] = pack_bf2(f1.x, f1.y); w[3] = pack_bf2(f1.z, f1.w);
        *(u32x4*)((char*)As + o2) = w;
      } else {
        gload_lds16((const char*)((const unsigned short*)Ap +
                        (size_t)(m0 + row) * 1024 + kt * 64) + colb,
                    (char*)As + i * 4096 + wave * 1024);
      }
      if constexpr (BF32) {
        const float* src = (const float*)Btp + (size_t)(n0 + row) * 1024 + kt * 64 + (colb >> 1);
        float4 f0 = *(const float4*)src;
        float4 f1 = *(const float4*)(src + 4);
        u32x4 w;
        w[0] = pack_bf2(f0.x, f0.y); w[1] = pack_bf2(f0.z, f0.w);
        w[2] = pack_bf2(f1.x, f1.y); w[3] = pack_bf2(f1.z, f1.w);
        *(u32x4*)((char*)Bs + o2) = w;
      } else {
        gload_lds16((const char*)((const unsigned short*)Btp +
                        (size_t)(n0 + row) * 1024 + kt * 64) + colb,
                    (char*)Bs + i * 4096 + wave * 1024);
      }
    }
    __syncthreads();
#pragma unroll
    for (int kk = 0; kk < 2; ++kk) {
      bf16x8 af[4], bf[4];
#pragma unroll
      for (int m = 0; m < 4; ++m) af[m] = *(const bf16x8*)(Afr + m * 2048 + kk * 64);
#pragma unroll
      for (int n = 0; n < 4; ++n) bf[n] = *(const bf16x8*)(Bfr + n * 2048 + kk * 64);
#pragma unroll
      for (int m = 0; m < 4; ++m)
#pragma unroll
        for (int n = 0; n < 4; ++n) acc[m][n] = MFMA16(af[m], bf[n], acc[m][n]);
    }
  }

  const int rbase = m0 + wr * 64 + ((lane >> 4) << 2);
  const int cbase = n0 + wc * 64 + (lane & 15);
#pragma unroll
  for (int m = 0; m < 4; ++m)
#pragma unroll
    for (int n = 0; n < 4; ++n)
#pragma unroll
      for (int r = 0; r < 4; ++r) {
        int row = rbase + m * 16 + r;
        int col = cbase + n * 16;
        float v = acc[m][n][r] * scale;
        if constexpr (CMODE == 0) {
          ((float*)C)[(size_t)row * 1024 + col] = v;
        } else if constexpr (CMODE == 1) {
          int b = row >> 11, t = row & 2047, h = col >> 6, k = col & 63;
          ((unsigned short*)C)[(((size_t)(b * H_ + h) * T_) + t) * 64 + k] = f2bf(v);
        } else {
          int h = row >> 6, vv = row & 63, b = col >> 11, t = col & 2047;
          ((unsigned short*)C)[(((size_t)(b * H_ + h) * 64) + vv) * T_ + t] = f2bf(v);
        }
      }
}

// All three projection GEMMs in ONE dispatch (1536 blocks), XCD-swizzled so
// blocks sharing an A-panel co-locate on one XCD's L2. Activation operands
// read directly from f32 inputs (conversion fused into staging).
__global__ __launch_bounds__(256) void gemm_proj3(
    const float* __restrict__ Q, const unsigned short* __restrict__ WqT,
    unsigned short* __restrict__ Qh,
    const float* __restrict__ K, const unsigned short* __restrict__ WkT,
    unsigned short* __restrict__ Kh,
    const unsigned short* __restrict__ WvT, const float* __restrict__ V,
    unsigned short* __restrict__ VhT, float qscale) {
  const int bid = blockIdx.x;
  const int wid = (bid & 7) * 192 + (bid >> 3);   // 1536/8 = 192, bijective
  const int seg = wid / 512, sub = wid % 512;
  if (seg == 0)      gemm_body<true,  false, 1>(Q,   WqT, Qh,  sub, 8,  qscale);
  else if (seg == 1) gemm_body<true,  false, 1>(K,   WkT, Kh,  sub, 8,  1.0f);
  else               gemm_body<false, true,  2>(WvT, V,   VhT, sub, 64, 1.0f);
}

__global__ __launch_bounds__(256) void gemm_out(
    const unsigned short* __restrict__ A, const unsigned short* __restrict__ Bt,
    float* __restrict__ C) {
  const int bid = blockIdx.x;
  const int wid = (bid & 7) * 64 + (bid >> 3);    // 512/8 = 64, bijective
  gemm_body<false, false, 0>(A, Bt, C, wid, 8, 1.0f);
}

// ---------------------------------------------------------------------------
// Flash attention (causal), v6: v5 + T12 in-register P redistribution.
// P never touches LDS: after cvt_pk packing, permlane32_swap+permlane16_swap
// rearrange pk[c][d] dwords into the PV A-fragment layout
// (lane(lq,hi) <- P[q=lq][s=ks*32+hi*8..+7]). LDS 32KB -> 5 blocks/CU.
// ---------------------------------------------------------------------------
__global__ __launch_bounds__(256, 5) void attn_fwd(
    const unsigned short* __restrict__ Qh, const unsigned short* __restrict__ Kh,
    const unsigned short* __restrict__ VhT, unsigned short* __restrict__ Abuf) {
  __shared__ unsigned short Ks[2][64 * 64];   // [s][k], swizzled, 8KB each
  __shared__ unsigned short Vs[2][64 * 64];   // [v][s], swizzled, 8KB each

  const int bid = blockIdx.x;
  const int wid = ((bid & 7) << 7) | (bid >> 3);  // XCD swizzle (1024 % 8 == 0)
  const int p  = wid & 15;                   // pair index
  const int bh = wid >> 4;                   // b*H + h
  const int b = bh >> 4, h = bh & 15;
  const int tid = threadIdx.x;
  const int wave = tid >> 6, lane = tid & 63;
  const int lq = lane & 15;
  const int hi = lane >> 4;
  const int nkt = 32 - p;                    // heavy tile KV count

  int q0[2];
  q0[0] = (31 - p) * 64 + wave * 16;         // heavy
  q0[1] = p * 64 + wave * 16;                // light

  const char* Kbase = (const char*)(Kh + (size_t)bh * T_ * 64);
  const char* Vbase = (const char*)(VhT + (size_t)bh * 64 * T_);

  // staging geometry: linear LDS dest, inverse-swizzled global source col
  int srow[2], scol[2], sdst[2];
#pragma unroll
  for (int i = 0; i < 2; ++i) {
    int o = i * 4096 + wave * 1024 + lane * 16;
    srow[i] = o >> 7;
    scol[i] = (o & 127) ^ ((srow[i] & 7) << 4);
    sdst[i] = i * 4096 + wave * 1024;        // wave-uniform dest (HW adds lane*16)
  }

  // Q fragments per tile
  bf16x8 qf[2][2];
#pragma unroll
  for (int j = 0; j < 2; ++j) {
    const unsigned short* qp = Qh + ((size_t)bh * T_ + q0[j] + lq) * 64 + hi * 8;
    qf[j][0] = *(const bf16x8*)qp;
    qf[j][1] = *(const bf16x8*)(qp + 32);
  }

  f32x4 o[2][4];
#pragma unroll
  for (int j = 0; j < 2; ++j)
#pragma unroll
    for (int n = 0; n < 4; ++n) o[j][n] = 0.f;
  float m_run[2] = {-1e30f, -1e30f}, l_run[2] = {0.f, 0.f};

  auto stage = [&](int buf, int kt) {
#pragma unroll
    for (int i = 0; i < 2; ++i) {
      gload_lds16(Kbase + (size_t)(kt * 64 + srow[i]) * 128 + scol[i],
                  (char*)Ks[buf] + sdst[i]);
      gload_lds16(Vbase + (size_t)srow[i] * (T_ * 2) + kt * 128 + scol[i],
                  (char*)Vs[buf] + sdst[i]);
    }
  };

  // prologue: stage tile 0
  stage(0, 0);
  asm volatile("s_waitcnt vmcnt(0)" ::: "memory");
  __builtin_amdgcn_s_barrier();

  int cur = 0;
  for (int kt = 0; kt < nkt; ++kt) {
    const int s0 = kt * 64;
    if (kt + 1 < nkt) stage(cur ^ 1, kt + 1);   // prefetch overlaps compute

    const char* KsB = (const char*)Ks[cur];
    const char* VsB = (const char*)Vs[cur];

#pragma unroll
    for (int j = 0; j < 2; ++j) {
      if (j == 1 && kt > p) continue;          // light tile done (block-uniform)

      // ---- QK^T: S^T[s][q] ----
      f32x4 sc[4];
      __builtin_amdgcn_s_setprio(1);
#pragma unroll
      for (int c = 0; c < 4; ++c) {
        int r = c * 16 + lq;
        const char* kb = KsB + r * 128;
        int sw = (r & 7) << 4;
        bf16x8 ka0 = *(const bf16x8*)(kb + ((hi * 16) ^ sw));
        bf16x8 ka1 = *(const bf16x8*)(kb + ((64 + hi * 16) ^ sw));
        f32x4 z = 0.f;
        z = MFMA16(ka0, qf[j][0], z);
        sc[c] = MFMA16(ka1, qf[j][1], z);
      }
      __builtin_amdgcn_s_setprio(0);

      if (s0 + 63 > q0[j]) {                   // diagonal tile: element mask
        int qg = q0[j] + lq;
#pragma unroll
        for (int c = 0; c < 4; ++c)
#pragma unroll
          for (int r = 0; r < 4; ++r) {
            int sg = s0 + c * 16 + hi * 4 + r;
            if (sg > qg) sc[c][r] = -1e30f;
          }
      }

      // ---- online softmax (log2 domain), row q = lane&15 lane-local ----
      float pmax = sc[0][0];
#pragma unroll
      for (int c = 0; c < 4; ++c)
#pragma unroll
        for (int r = 0; r < 4; ++r) pmax = fmaxf(pmax, sc[c][r]);
      pmax = fmaxf(pmax, __shfl_xor(pmax, 16));
      pmax = fmaxf(pmax, __shfl_xor(pmax, 32));

      if (!__all(pmax - m_run[j] <= 8.f)) {    // defer-max (T13)
        float mnew = fmaxf(m_run[j], pmax);
        float corr = __builtin_amdgcn_exp2f(m_run[j] - mnew);
        float cr[4];
#pragma unroll
        for (int r = 0; r < 4; ++r) cr[r] = __shfl(corr, hi * 4 + r);
#pragma unroll
        for (int n = 0; n < 4; ++n)
#pragma unroll
          for (int r = 0; r < 4; ++r) o[j][n][r] *= cr[r];
        l_run[j] *= corr;
        m_run[j] = mnew;
      }

      float psum = 0.f;
#pragma unroll
      for (int c = 0; c < 4; ++c)
#pragma unroll
        for (int r = 0; r < 4; ++r) {
          float pv = __builtin_amdgcn_exp2f(sc[c][r] - m_run[j]);
          sc[c][r] = pv;
          psum += pv;
        }
      psum += __shfl_xor(psum, 16);
      psum += __shfl_xor(psum, 32);
      l_run[j] += psum;

      // ---- pack P to bf16 dword pairs (in-register) ----
      unsigned pk[4][2];
#pragma unroll
      for (int c = 0; c < 4; ++c) {
        pk[c][0] = pack_bf2(sc[c][0], sc[c][1]);
        pk[c][1] = pack_bf2(sc[c][2], sc[c][3]);
      }

      // ---- O += P @ V, P redistributed via permlane swaps (T12) ----
      // chain (A,B) -> {permlane32_swap; permlane16_swap} gives
      //   A' = [A.g0, A.g2, B.g0, B.g2]  (= pa dword for s-pairs hi*8+{0,1}/{2,3})
      //   B' = [A.g1, A.g3, B.g1, B.g3]  (= pa dword for s-pairs hi*8+{4,5}/{6,7})
      __builtin_amdgcn_s_setprio(1);
#pragma unroll
      for (int ks = 0; ks < 2; ++ks) {
        unsigned a0 = pk[2 * ks][0], b0 = pk[2 * ks + 1][0];
        unsigned a1 = pk[2 * ks][1], b1 = pk[2 * ks + 1][1];
        asm("v_permlane32_swap_b32 %0, %1" : "+v"(a0), "+v"(b0));
        asm("v_permlane16_swap_b32 %0, %1" : "+v"(a0), "+v"(b0));
        asm("v_permlane32_swap_b32 %0, %1" : "+v"(a1), "+v"(b1));
        asm("v_permlane16_swap_b32 %0, %1" : "+v"(a1), "+v"(b1));
        u32x4 pau;
        pau[0] = a0; pau[1] = a1; pau[2] = b0; pau[3] = b1;
        bf16x8 pa = __builtin_bit_cast(bf16x8, pau);
#pragma unroll
        for (int n = 0; n < 4; ++n) {
          int rv = n * 16 + lq;
          bf16x8 vb = *(const bf16x8*)(VsB + rv * 128 +
                                       ((ks * 64 + hi * 16) ^ ((rv & 7) << 4)));
          o[j][n] = MFMA16(pa, vb, o[j][n]);
        }
      }
      __builtin_amdgcn_s_setprio(0);
    }

    // tile boundary: drain prefetch, sync all waves
    asm volatile("s_waitcnt vmcnt(0)" ::: "memory");
    __builtin_amdgcn_s_barrier();
    cur ^= 1;
  }

  // finalize: divide by l, write A [b*T+t][h*64+v] bf16
#pragma unroll
  for (int j = 0; j < 2; ++j) {
    float inv[4];
#pragma unroll
    for (int r = 0; r < 4; ++r)
      inv[r] = 1.0f / __shfl(l_run[j], hi * 4 + r);
#pragma unroll
    for (int r = 0; r < 4; ++r) {
      int t = q0[j] + hi * 4 + r;
      size_t base = ((size_t)b * T_ + t) * 1024 + h * 64 + lq;
#pragma unroll
      for (int n = 0; n < 4; ++n)
        Abuf[base + n * 16] = f2bf(o[j][n][r] * inv[r]);
    }
  }
}

// ---------------------------------------------------------------------------
extern "C" void kernel_launch(void* const* d_in, const int* in_sizes, int n_in,
                              void* d_out, int out_size, void* d_ws, size_t ws_size,
                              hipStream_t stream) {
  (void)in_sizes; (void)n_in; (void)out_size; (void)ws_size;
  const float* Q  = (const float*)d_in[0];
  const float* K  = (const float*)d_in[1];
  const float* V  = (const float*)d_in[2];
  const float* WQ = (const float*)d_in[3];
  const float* WK = (const float*)d_in[4];
  const float* WV = (const float*)d_in[5];
  const float* WO = (const float*)d_in[6];
  float* out = (float*)d_out;
  char* ws = (char*)d_ws;

  const size_t SZ_ACT = (size_t)8192 * 1024 * 2;  // 16.78 MB
  const size_t SZ_W   = (size_t)1024 * 1024 * 2;  //  2.10 MB
  unsigned short* WqT = (unsigned short*)(ws);
  unsigned short* WkT = (unsigned short*)(ws + SZ_W);
  unsigned short* WvT = (unsigned short*)(ws + 2 * SZ_W);
  unsigned short* WOt = (unsigned short*)(ws + 3 * SZ_W);
  unsigned short* Qh  = (unsigned short*)(ws + 4 * SZ_W);
  unsigned short* Kh  = (unsigned short*)(ws + 4 * SZ_W + SZ_ACT);
  unsigned short* VhT = (unsigned short*)(ws + 4 * SZ_W + 2 * SZ_ACT);
  unsigned short* Abuf = (unsigned short*)(ws + 4 * SZ_W + 3 * SZ_ACT);

  // 1) transpose weights to B^T bf16 (one dispatch)
  trans4<<<1024, 256, 0, stream>>>(WQ, WK, WV, WO, WqT, WkT, WvT, WOt);

  // 2) projections (one dispatch; activations converted in-staging;
  //    Q scaled by log2(e)/sqrt(dk))
  const float qscale = 1.4426950408889634f / 8.0f;
  gemm_proj3<<<1536, 256, 0, stream>>>(Q, WqT, Qh, K, WkT, Kh,
                                       WvT, V, VhT, qscale);

  // 3) causal flash attention (paired q-tiles, XCD-swizzled, in-reg P)
  attn_fwd<<<1024, 256, 0, stream>>>(Qh, Kh, VhT, Abuf);

  // 4) output projection -> f32
  gemm_out<<<512, 256, 0, stream>>>(Abuf, WOt, out);
}

// Round 7
// 226.829 us; speedup vs baseline: 2.7293x; 1.0026x over previous
//
#include <hip/hip_runtime.h>
#include <hip/hip_bf16.h>

// Problem constants (fixed)
#define B_ 4
#define T_ 2048
#define D_ 1024
#define H_ 16
// DK = DV = 64

typedef __attribute__((ext_vector_type(8))) short bf16x8;
typedef __attribute__((ext_vector_type(4))) float f32x4;
typedef __attribute__((ext_vector_type(4))) unsigned short u16x4;
typedef __attribute__((ext_vector_type(4))) unsigned int u32x4;

__device__ __forceinline__ unsigned short f2bf(float x) {
  union { float f; unsigned u; } v; v.f = x;
  unsigned r = v.u + 0x7fffu + ((v.u >> 16) & 1u);   // RNE
  return (unsigned short)(r >> 16);
}

__device__ __forceinline__ unsigned pack_bf2(float a, float b) {
  __hip_bfloat162 h = __float22bfloat162_rn(float2{a, b});
  union { __hip_bfloat162 h; unsigned u; } cv; cv.h = h; return cv.u;
}

__device__ __forceinline__ void gload_lds16(const void* g, void* l) {
  __builtin_amdgcn_global_load_lds(
      (const __attribute__((address_space(1))) unsigned int*)g,
      (__attribute__((address_space(3))) unsigned int*)l, 16, 0, 0);
}

#define MFMA16(a, b, c) __builtin_amdgcn_mfma_f32_16x16x32_bf16((a), (b), (c), 0, 0, 0)

// ---------------------------------------------------------------------------
// Weight transposes, all four in ONE dispatch (1024 blocks).
// seg 0..2: [16][1024][64] f32 -> [16*64][1024] bf16 (256 blocks each)
// seg 3:    [1024][1024] f32 -> [1024][1024] bf16 transposed (256 blocks)
// ---------------------------------------------------------------------------
__global__ __launch_bounds__(256) void trans4(
    const float* __restrict__ WQ, const float* __restrict__ WK,
    const float* __restrict__ WV, const float* __restrict__ WO,
    unsigned short* __restrict__ WqT, unsigned short* __restrict__ WkT,
    unsigned short* __restrict__ WvT, unsigned short* __restrict__ WOt) {
  __shared__ float tile[64][65];
  const int seg = blockIdx.x >> 8;
  const int sub = blockIdx.x & 255;
  const float* src = (seg == 0) ? WQ : (seg == 1) ? WK : (seg == 2) ? WV : WO;
  unsigned short* dst = (seg == 0) ? WqT : (seg == 1) ? WkT : (seg == 2) ? WvT : WOt;
  const int DK = (seg == 3) ? 1024 : 64;
  int h, dt, ktile;
  if (seg == 3) { h = 0; dt = sub >> 4; ktile = sub & 15; }
  else          { h = sub >> 4; dt = sub & 15; ktile = 0; }
  const int d0 = dt * 64, k0 = ktile * 64;
  const int tx = threadIdx.x & 63, ty = threadIdx.x >> 6;
  const float* s = src + (size_t)h * 1024 * DK;
#pragma unroll
  for (int i = 0; i < 16; ++i) {
    int row = i * 4 + ty;
    tile[row][tx] = s[(size_t)(d0 + row) * DK + k0 + tx];
  }
  __syncthreads();
  unsigned short* dd = dst + (size_t)h * DK * 1024;
#pragma unroll
  for (int i = 0; i < 16; ++i) {
    int kk = i * 4 + ty;
    dd[(size_t)(k0 + kk) * 1024 + d0 + tx] = f2bf(tile[tx][kk]);
  }
}

// ---------------------------------------------------------------------------
// GEMM body: C[m][n] = sum_k A[m][k] * Bt[n][k], K=1024, tile 128x128.
// AF32/BF32: that operand is f32 in global, converted to bf16 during staging
// (reg-staged: 2x float4 load -> 4x cvt_pk -> ds_write_b128). bf16 operands
// stage via global_load_lds width-16.
// CMODE 0: C f32 [M][1024]
// CMODE 1: C bf16 per-head [B,H,T,64]   (row = b*T+t, col = h*64+k)
// CMODE 2: C bf16 VhT [B,H,64,T]        (row = h*64+v, col = b*T+t)
// ---------------------------------------------------------------------------
template <bool AF32, bool BF32, int CMODE>
__device__ __forceinline__ void gemm_body(
    const void* __restrict__ Ap, const void* __restrict__ Btp,
    void* __restrict__ C, int bid, int nTilesN, float scale) {
  __shared__ unsigned short As[128 * 64];
  __shared__ unsigned short Bs[128 * 64];
  const int bm = bid / nTilesN, bn = bid % nTilesN;
  const int m0 = bm * 128, n0 = bn * 128;
  const int tid = threadIdx.x;
  const int wave = tid >> 6, lane = tid & 63;
  const int wr = wave >> 1, wc = wave & 1;

  f32x4 acc[4][4];
#pragma unroll
  for (int m = 0; m < 4; ++m)
#pragma unroll
    for (int n = 0; n < 4; ++n) acc[m][n] = 0.f;

  const int soff = wave * 1024 + lane * 16;
  const char* Afr = (const char*)As + (wr * 64 + (lane & 15)) * 128 + (lane >> 4) * 16;
  const char* Bfr = (const char*)Bs + (wc * 64 + (lane & 15)) * 128 + (lane >> 4) * 16;

  for (int kt = 0; kt < 16; ++kt) {
    __syncthreads();
#pragma unroll
    for (int i = 0; i < 4; ++i) {
      int o2 = i * 4096 + soff;
      int row = o2 >> 7, colb = o2 & 127;
      if constexpr (AF32) {
        const float* src = (const float*)Ap + (size_t)(m0 + row) * 1024 + kt * 64 + (colb >> 1);
        float4 f0 = *(const float4*)src;
        float4 f1 = *(const float4*)(src + 4);
        u32x4 w;
        w[0] = pack_bf2(f0.x, f0.y); w[1] = pack_bf2(f0.z, f0.w);
        w[2] = pack_bf2(f1.x, f1.y); w[3] = pack_bf2(f1.z, f1.w);
        *(u32x4*)((char*)As + o2) = w;
      } else {
        gload_lds16((const char*)((const unsigned short*)Ap +
                        (size_t)(m0 + row) * 1024 + kt * 64) + colb,
                    (char*)As + i * 4096 + wave * 1024);
      }
      if constexpr (BF32) {
        const float* src = (const float*)Btp + (size_t)(n0 + row) * 1024 + kt * 64 + (colb >> 1);
        float4 f0 = *(const float4*)src;
        float4 f1 = *(const float4*)(src + 4);
        u32x4 w;
        w[0] = pack_bf2(f0.x, f0.y); w[1] = pack_bf2(f0.z, f0.w);
        w[2] = pack_bf2(f1.x, f1.y); w[3] = pack_bf2(f1.z, f1.w);
        *(u32x4*)((char*)Bs + o2) = w;
      } else {
        gload_lds16((const char*)((const unsigned short*)Btp +
                        (size_t)(n0 + row) * 1024 + kt * 64) + colb,
                    (char*)Bs + i * 4096 + wave * 1024);
      }
    }
    __syncthreads();
#pragma unroll
    for (int kk = 0; kk < 2; ++kk) {
      bf16x8 af[4], bf[4];
#pragma unroll
      for (int m = 0; m < 4; ++m) af[m] = *(const bf16x8*)(Afr + m * 2048 + kk * 64);
#pragma unroll
      for (int n = 0; n < 4; ++n) bf[n] = *(const bf16x8*)(Bfr + n * 2048 + kk * 64);
#pragma unroll
      for (int m = 0; m < 4; ++m)
#pragma unroll
        for (int n = 0; n < 4; ++n) acc[m][n] = MFMA16(af[m], bf[n], acc[m][n]);
    }
  }

  const int rbase = m0 + wr * 64 + ((lane >> 4) << 2);
  const int cbase = n0 + wc * 64 + (lane & 15);
#pragma unroll
  for (int m = 0; m < 4; ++m)
#pragma unroll
    for (int n = 0; n < 4; ++n)
#pragma unroll
      for (int r = 0; r < 4; ++r) {
        int row = rbase + m * 16 + r;
        int col = cbase + n * 16;
        float v = acc[m][n][r] * scale;
        if constexpr (CMODE == 0) {
          ((float*)C)[(size_t)row * 1024 + col] = v;
        } else if constexpr (CMODE == 1) {
          int b = row >> 11, t = row & 2047, h = col >> 6, k = col & 63;
          ((unsigned short*)C)[(((size_t)(b * H_ + h) * T_) + t) * 64 + k] = f2bf(v);
        } else {
          int h = row >> 6, vv = row & 63, b = col >> 11, t = col & 2047;
          ((unsigned short*)C)[(((size_t)(b * H_ + h) * 64) + vv) * T_ + t] = f2bf(v);
        }
      }
}

// All three projection GEMMs in ONE dispatch (1536 blocks), XCD-swizzled so
// blocks sharing an A-panel co-locate on one XCD's L2. Activation operands
// read directly from f32 inputs (conversion fused into staging).
__global__ __launch_bounds__(256) void gemm_proj3(
    const float* __restrict__ Q, const unsigned short* __restrict__ WqT,
    unsigned short* __restrict__ Qh,
    const float* __restrict__ K, const unsigned short* __restrict__ WkT,
    unsigned short* __restrict__ Kh,
    const unsigned short* __restrict__ WvT, const float* __restrict__ V,
    unsigned short* __restrict__ VhT, float qscale) {
  const int bid = blockIdx.x;
  const int wid = (bid & 7) * 192 + (bid >> 3);   // 1536/8 = 192, bijective
  const int seg = wid / 512, sub = wid % 512;
  if (seg == 0)      gemm_body<true,  false, 1>(Q,   WqT, Qh,  sub, 8,  qscale);
  else if (seg == 1) gemm_body<true,  false, 1>(K,   WkT, Kh,  sub, 8,  1.0f);
  else               gemm_body<false, true,  2>(WvT, V,   VhT, sub, 64, 1.0f);
}

__global__ __launch_bounds__(256) void gemm_out(
    const unsigned short* __restrict__ A, const unsigned short* __restrict__ Bt,
    float* __restrict__ C) {
  const int bid = blockIdx.x;
  const int wid = (bid & 7) * 64 + (bid >> 3);    // 512/8 = 64, bijective
  gemm_body<false, false, 0>(A, Bt, C, wid, 8, 1.0f);
}

// ---------------------------------------------------------------------------
// Flash attention (causal), v6: v5 + T12 in-register P redistribution.
// P never touches LDS: after cvt_pk packing, permlane32_swap+permlane16_swap
// rearrange pk[c][d] dwords into the PV A-fragment layout
// (lane(lq,hi) <- P[q=lq][s=ks*32+hi*8..+7]). LDS 32KB -> 5 blocks/CU.
// ---------------------------------------------------------------------------
__global__ __launch_bounds__(256, 5) void attn_fwd(
    const unsigned short* __restrict__ Qh, const unsigned short* __restrict__ Kh,
    const unsigned short* __restrict__ VhT, unsigned short* __restrict__ Abuf) {
  __shared__ unsigned short Ks[2][64 * 64];   // [s][k], swizzled, 8KB each
  __shared__ unsigned short Vs[2][64 * 64];   // [v][s], swizzled, 8KB each

  const int bid = blockIdx.x;
  const int wid = ((bid & 7) << 7) | (bid >> 3);  // XCD swizzle (1024 % 8 == 0)
  const int p  = wid & 15;                   // pair index
  const int bh = wid >> 4;                   // b*H + h
  const int b = bh >> 4, h = bh & 15;
  const int tid = threadIdx.x;
  const int wave = tid >> 6, lane = tid & 63;
  const int lq = lane & 15;
  const int hi = lane >> 4;
  const int nkt = 32 - p;                    // heavy tile KV count

  int q0[2];
  q0[0] = (31 - p) * 64 + wave * 16;         // heavy
  q0[1] = p * 64 + wave * 16;                // light

  const char* Kbase = (const char*)(Kh + (size_t)bh * T_ * 64);
  const char* Vbase = (const char*)(VhT + (size_t)bh * 64 * T_);

  // staging geometry: linear LDS dest, inverse-swizzled global source col
  int srow[2], scol[2], sdst[2];
#pragma unroll
  for (int i = 0; i < 2; ++i) {
    int o = i * 4096 + wave * 1024 + lane * 16;
    srow[i] = o >> 7;
    scol[i] = (o & 127) ^ ((srow[i] & 7) << 4);
    sdst[i] = i * 4096 + wave * 1024;        // wave-uniform dest (HW adds lane*16)
  }

  // Q fragments per tile
  bf16x8 qf[2][2];
#pragma unroll
  for (int j = 0; j < 2; ++j) {
    const unsigned short* qp = Qh + ((size_t)bh * T_ + q0[j] + lq) * 64 + hi * 8;
    qf[j][0] = *(const bf16x8*)qp;
    qf[j][1] = *(const bf16x8*)(qp + 32);
  }

  f32x4 o[2][4];
#pragma unroll
  for (int j = 0; j < 2; ++j)
#pragma unroll
    for (int n = 0; n < 4; ++n) o[j][n] = 0.f;
  float m_run[2] = {-1e30f, -1e30f}, l_run[2] = {0.f, 0.f};

  auto stage = [&](int buf, int kt) {
#pragma unroll
    for (int i = 0; i < 2; ++i) {
      gload_lds16(Kbase + (size_t)(kt * 64 + srow[i]) * 128 + scol[i],
                  (char*)Ks[buf] + sdst[i]);
      gload_lds16(Vbase + (size_t)srow[i] * (T_ * 2) + kt * 128 + scol[i],
                  (char*)Vs[buf] + sdst[i]);
    }
  };

  // prologue: stage tile 0
  stage(0, 0);
  asm volatile("s_waitcnt vmcnt(0)" ::: "memory");
  __builtin_amdgcn_s_barrier();

  int cur = 0;
  for (int kt = 0; kt < nkt; ++kt) {
    const int s0 = kt * 64;
    if (kt + 1 < nkt) stage(cur ^ 1, kt + 1);   // prefetch overlaps compute

    const char* KsB = (const char*)Ks[cur];
    const char* VsB = (const char*)Vs[cur];

#pragma unroll
    for (int j = 0; j < 2; ++j) {
      if (j == 1 && kt > p) continue;          // light tile done (block-uniform)

      // ---- QK^T: S^T[s][q] ----
      f32x4 sc[4];
      __builtin_amdgcn_s_setprio(1);
#pragma unroll
      for (int c = 0; c < 4; ++c) {
        int r = c * 16 + lq;
        const char* kb = KsB + r * 128;
        int sw = (r & 7) << 4;
        bf16x8 ka0 = *(const bf16x8*)(kb + ((hi * 16) ^ sw));
        bf16x8 ka1 = *(const bf16x8*)(kb + ((64 + hi * 16) ^ sw));
        f32x4 z = 0.f;
        z = MFMA16(ka0, qf[j][0], z);
        sc[c] = MFMA16(ka1, qf[j][1], z);
      }
      __builtin_amdgcn_s_setprio(0);

      if (s0 + 63 > q0[j]) {                   // diagonal tile: element mask
        int qg = q0[j] + lq;
#pragma unroll
        for (int c = 0; c < 4; ++c)
#pragma unroll
          for (int r = 0; r < 4; ++r) {
            int sg = s0 + c * 16 + hi * 4 + r;
            if (sg > qg) sc[c][r] = -1e30f;
          }
      }

      // ---- online softmax (log2 domain), row q = lane&15 lane-local ----
      float pmax = sc[0][0];
#pragma unroll
      for (int c = 0; c < 4; ++c)
#pragma unroll
        for (int r = 0; r < 4; ++r) pmax = fmaxf(pmax, sc[c][r]);
      pmax = fmaxf(pmax, __shfl_xor(pmax, 16));
      pmax = fmaxf(pmax, __shfl_xor(pmax, 32));

      if (!__all(pmax - m_run[j] <= 8.f)) {    // defer-max (T13)
        float mnew = fmaxf(m_run[j], pmax);
        float corr = __builtin_amdgcn_exp2f(m_run[j] - mnew);
        float cr[4];
#pragma unroll
        for (int r = 0; r < 4; ++r) cr[r] = __shfl(corr, hi * 4 + r);
#pragma unroll
        for (int n = 0; n < 4; ++n)
#pragma unroll
          for (int r = 0; r < 4; ++r) o[j][n][r] *= cr[r];
        l_run[j] *= corr;
        m_run[j] = mnew;
      }

      float psum = 0.f;
#pragma unroll
      for (int c = 0; c < 4; ++c)
#pragma unroll
        for (int r = 0; r < 4; ++r) {
          float pv = __builtin_amdgcn_exp2f(sc[c][r] - m_run[j]);
          sc[c][r] = pv;
          psum += pv;
        }
      psum += __shfl_xor(psum, 16);
      psum += __shfl_xor(psum, 32);
      l_run[j] += psum;

      // ---- pack P to bf16 dword pairs (in-register) ----
      unsigned pk[4][2];
#pragma unroll
      for (int c = 0; c < 4; ++c) {
        pk[c][0] = pack_bf2(sc[c][0], sc[c][1]);
        pk[c][1] = pack_bf2(sc[c][2], sc[c][3]);
      }

      // ---- O += P @ V, P redistributed via permlane swaps (T12) ----
      // chain (A,B) -> {permlane32_swap; permlane16_swap} gives
      //   A' = [A.g0, A.g2, B.g0, B.g2]  (= pa dword for s-pairs hi*8+{0,1}/{2,3})
      //   B' = [A.g1, A.g3, B.g1, B.g3]  (= pa dword for s-pairs hi*8+{4,5}/{6,7})
      __builtin_amdgcn_s_setprio(1);
#pragma unroll
      for (int ks = 0; ks < 2; ++ks) {
        unsigned a0 = pk[2 * ks][0], b0 = pk[2 * ks + 1][0];
        unsigned a1 = pk[2 * ks][1], b1 = pk[2 * ks + 1][1];
        asm("v_permlane32_swap_b32 %0, %1" : "+v"(a0), "+v"(b0));
        asm("v_permlane16_swap_b32 %0, %1" : "+v"(a0), "+v"(b0));
        asm("v_permlane32_swap_b32 %0, %1" : "+v"(a1), "+v"(b1));
        asm("v_permlane16_swap_b32 %0, %1" : "+v"(a1), "+v"(b1));
        u32x4 pau;
        pau[0] = a0; pau[1] = a1; pau[2] = b0; pau[3] = b1;
        bf16x8 pa = __builtin_bit_cast(bf16x8, pau);
#pragma unroll
        for (int n = 0; n < 4; ++n) {
          int rv = n * 16 + lq;
          bf16x8 vb = *(const bf16x8*)(VsB + rv * 128 +
                                       ((ks * 64 + hi * 16) ^ ((rv & 7) << 4)));
          o[j][n] = MFMA16(pa, vb, o[j][n]);
        }
      }
      __builtin_amdgcn_s_setprio(0);
    }

    // tile boundary: drain prefetch, sync all waves
    asm volatile("s_waitcnt vmcnt(0)" ::: "memory");
    __builtin_amdgcn_s_barrier();
    cur ^= 1;
  }

  // finalize: divide by l, write A [b*T+t][h*64+v] bf16
#pragma unroll
  for (int j = 0; j < 2; ++j) {
    float inv[4];
#pragma unroll
    for (int r = 0; r < 4; ++r)
      inv[r] = 1.0f / __shfl(l_run[j], hi * 4 + r);
#pragma unroll
    for (int r = 0; r < 4; ++r) {
      int t = q0[j] + hi * 4 + r;
      size_t base = ((size_t)b * T_ + t) * 1024 + h * 64 + lq;
#pragma unroll
      for (int n = 0; n < 4; ++n)
        Abuf[base + n * 16] = f2bf(o[j][n][r] * inv[r]);
    }
  }
}

// ---------------------------------------------------------------------------
extern "C" void kernel_launch(void* const* d_in, const int* in_sizes, int n_in,
                              void* d_out, int out_size, void* d_ws, size_t ws_size,
                              hipStream_t stream) {
  (void)in_sizes; (void)n_in; (void)out_size; (void)ws_size;
  const float* Q  = (const float*)d_in[0];
  const float* K  = (const float*)d_in[1];
  const float* V  = (const float*)d_in[2];
  const float* WQ = (const float*)d_in[3];
  const float* WK = (const float*)d_in[4];
  const float* WV = (const float*)d_in[5];
  const float* WO = (const float*)d_in[6];
  float* out = (float*)d_out;
  char* ws = (char*)d_ws;

  const size_t SZ_ACT = (size_t)8192 * 1024 * 2;  // 16.78 MB
  const size_t SZ_W   = (size_t)1024 * 1024 * 2;  //  2.10 MB
  unsigned short* WqT = (unsigned short*)(ws);
  unsigned short* WkT = (unsigned short*)(ws + SZ_W);
  unsigned short* WvT = (unsigned short*)(ws + 2 * SZ_W);
  unsigned short* WOt = (unsigned short*)(ws + 3 * SZ_W);
  unsigned short* Qh  = (unsigned short*)(ws + 4 * SZ_W);
  unsigned short* Kh  = (unsigned short*)(ws + 4 * SZ_W + SZ_ACT);
  unsigned short* VhT = (unsigned short*)(ws + 4 * SZ_W + 2 * SZ_ACT);
  unsigned short* Abuf = (unsigned short*)(ws + 4 * SZ_W + 3 * SZ_ACT);

  // 1) transpose weights to B^T bf16 (one dispatch)
  trans4<<<1024, 256, 0, stream>>>(WQ, WK, WV, WO, WqT, WkT, WvT, WOt);

  // 2) projections (one dispatch; activations converted in-staging;
  //    Q scaled by log2(e)/sqrt(dk))
  const float qscale = 1.4426950408889634f / 8.0f;
  gemm_proj3<<<1536, 256, 0, stream>>>(Q, WqT, Qh, K, WkT, Kh,
                                       WvT, V, VhT, qscale);

  // 3) causal flash attention (paired q-tiles, XCD-swizzled, in-reg P)
  attn_fwd<<<1024, 256, 0, stream>>>(Qh, Kh, VhT, Abuf);

  // 4) output projection -> f32
  gemm_out<<<512, 256, 0, stream>>>(Abuf, WOt, out);
}